// Round 4
// baseline (729.203 us; speedup 1.0000x reference)
//
#include <hip/hip_runtime.h>
#include <hip/hip_bf16.h>

// LNNRegression: 3-sequential-phase design (no per-step barriers).
//  A: all 4 waves t-parallel -> rtau[512] (gate), z-trick for dx.
//  B: wave0 only, 512-step LTC recurrence (single-wave, self-ordered LDS),
//     pre computed on the fly; h rows streamed to d_ws (f32 or bf16).
//  C: all 4 waves t-parallel (stride 4): fusion + attention + ONLINE softmax
//     per wave; 4 partials merged; then heads.
// All dots as float2 pairs (v_pk_fma_f32 candidate).

#define T_ 512
#define D_ 31
#define L2E 1.4426950408889634f

__device__ __forceinline__ float fexp2(float x){ return __builtin_amdgcn_exp2f(x); }
__device__ __forceinline__ float frcp (float x){ return __builtin_amdgcn_rcpf(x); }
__device__ __forceinline__ float fast_tanh(float x){
    float e = fexp2(x * 2.8853900817779268f);
    return 1.0f - 2.0f * frcp(1.0f + e);
}
__device__ __forceinline__ float fast_sigmoid(float x){
    return frcp(1.0f + fexp2(x * -1.4426950408889634f));
}

struct f2 { float x, y; };

// acc += pairwise over 8 float4 (32 elems) against 16 f2 weights
#define DOT16PAIR(accv, warr, q4)                                  \
    do { _Pragma("unroll")                                         \
        for (int c_ = 0; c_ < 8; ++c_) {                           \
            float4 q_ = (q4)[c_];                                  \
            accv.x += (warr)[2*c_].x   * q_.x;                     \
            accv.y += (warr)[2*c_].y   * q_.y;                     \
            accv.x += (warr)[2*c_+1].x * q_.z;                     \
            accv.y += (warr)[2*c_+1].y * q_.w;                     \
        } } while (0)

template <typename HT>
__launch_bounds__(256, 4)
__global__ void lnn3(
    const float* __restrict__ X,
    const float* __restrict__ fg_w1, const float* __restrict__ fg_b1,
    const float* __restrict__ fg_w2, const float* __restrict__ fg_b2,
    const float* __restrict__ fwin,  const float* __restrict__ fbin,
    const float* __restrict__ fwrec,
    const float* __restrict__ swin,  const float* __restrict__ sbin,
    const float* __restrict__ swrec,
    const float* __restrict__ fu_w,  const float* __restrict__ fu_b,
    const float* __restrict__ at_w1, const float* __restrict__ at_b1,
    const float* __restrict__ at_w2, const float* __restrict__ at_b2,
    const float* __restrict__ d_w1,  const float* __restrict__ d_b1,
    const float* __restrict__ d_w2,  const float* __restrict__ d_b2,
    const float* __restrict__ o_w1,  const float* __restrict__ o_b1,
    const float* __restrict__ o_w2,  const float* __restrict__ o_b2,
    const float* __restrict__ o_w3,  const float* __restrict__ o_b3,
    const float* __restrict__ i_w1,  const float* __restrict__ i_b1,
    const float* __restrict__ i_w2,  const float* __restrict__ i_b2,
    float* __restrict__ out, HT* __restrict__ hseq, int B)
{
    const int b    = blockIdx.x;
    const int tx   = threadIdx.x;
    const int wid  = tx >> 6;
    const int lane = tx & 63;
    const int u    = lane & 31;
    const int hb32 = lane & 32;

    __shared__ float xstg[4][32];
    __shared__ float hbuf[2][64];
    __shared__ float rtau[512];
    __shared__ float ltcS[4][64];
    __shared__ float mM[4], mS[4], mC[4][64];
    __shared__ float ctx_sh[64];

    if (lane == 31) xstg[wid][31] = 0.0f;     // pad stays 0 forever

    // =================== Phase A: gate -> rtau ===================
    {
        f2 wg[16];
        const float* g = fg_w1 + u * 62;
        #pragma unroll
        for (int j = 0; j < 16; ++j) {
            int j0 = 2*j, j1 = 2*j + 1;
            float a0, a1;
            if (lane < 32) {
                a0 = g[j0] + g[31 + j0];
                a1 = (j1 < 31) ? (g[j1] + g[31 + j1]) : 0.0f;
            } else {
                a0 = g[31 + j0];
                a1 = (j1 < 31) ? g[31 + j1] : 0.0f;
            }
            wg[j].x = a0; wg[j].y = a1;
        }
        const float b1  = (lane < 32) ? fg_b1[u] : 0.0f;
        const float w2u = fg_w2[u];
        const float b2s = fg_b2[0];

        const int t0 = wid * 128;
        const int rp = (t0 == 0) ? 0 : t0 - 1;
        float xr = 0.0f;
        if (lane < 31) xr = X[((size_t)b * T_ + rp) * D_ + lane];
        __syncthreads();                       // pad init visible
        if (lane < 31) xstg[wid][lane] = xr;
        const float4* xq4 = (const float4*)(&xstg[wid][0]);
        f2 acc0 = {0.f, 0.f};
        DOT16PAIR(acc0, wg, xq4);
        float y_prev = __shfl_xor(acc0.x + acc0.y, 32);
        if (lane < 31) xr = X[((size_t)b * T_ + t0) * D_ + lane];

        for (int k = 0; k < 128; ++k) {
            const int t = t0 + k;
            if (lane < 31) xstg[wid][lane] = xr;
            const int tn = (t + 1 < T_) ? t + 1 : T_ - 1;
            float xrn = 0.0f;
            if (lane < 31) xrn = X[((size_t)b * T_ + tn) * D_ + lane];
            f2 acc = {0.f, 0.f};
            DOT16PAIR(acc, wg, xq4);
            float ag = acc.x + acc.y;
            float yt = __shfl_xor(ag, 32);     // lanes<32: Bm.x_t
            float gg = fast_tanh(ag - y_prev + b1);
            y_prev = yt;
            float v = gg * w2u;
            v += __shfl_xor(v, 1);  v += __shfl_xor(v, 2);
            v += __shfl_xor(v, 4);  v += __shfl_xor(v, 8);
            v += __shfl_xor(v, 16);
            float cs = fast_sigmoid(v + b2s);
            if (lane == 0) rtau[t] = frcp(10.0f - 9.99f * cs);
            xr = xrn;
        }
    }
    __syncthreads();

    // =================== Phase B: LTC recurrence (wave0) ===================
    if (wid == 0) {
        f2 wp[16], wr[16];
        {
            const float* pw = (lane < 32) ? (fwin + u * 31) : (swin + u * 31);
            #pragma unroll
            for (int j = 0; j < 16; ++j) {
                wp[j].x = pw[2*j];
                wp[j].y = (2*j + 1 < 31) ? pw[2*j + 1] : 0.0f;
            }
            const float* rw = (lane < 32) ? (fwrec + u * 32) : (swrec + u * 32);
            #pragma unroll
            for (int j = 0; j < 16; ++j) { wr[j].x = rw[2*j]; wr[j].y = rw[2*j+1]; }
        }
        const float preb = (lane < 32) ? fbin[u] : sbin[u];
        hbuf[0][lane] = 0.0f;
        float h = 0.0f;
        float xr = 0.0f;
        if (lane < 31) xr = X[(size_t)b * T_ * D_ + lane];
        const float4* xq4 = (const float4*)(&xstg[0][0]);

        for (int t = 0; t < T_; ++t) {
            if (lane < 31) xstg[0][lane] = xr;
            const int tn = (t + 1 < T_) ? t + 1 : T_ - 1;
            float xrn = 0.0f;
            if (lane < 31) xrn = X[((size_t)b * T_ + tn) * D_ + lane];
            const float rt = (lane < 32) ? rtau[t] : 0.2f;
            f2 pa = {0.f, 0.f};
            DOT16PAIR(pa, wp, xq4);
            const float4* hq4 = (const float4*)(&hbuf[t & 1][hb32]);
            f2 ha = {0.f, 0.f};
            DOT16PAIR(ha, wr, hq4);
            float upd = fast_tanh(ha.x + ha.y + pa.x + pa.y + preb);
            h += (upd - h) * rt;
            hbuf[(t + 1) & 1][lane] = h;
            if constexpr (sizeof(HT) == 4)
                hseq[(((size_t)b * T_ + t) << 6) + lane] = (HT)h;
            else
                ((__hip_bfloat16*)hseq)[(((size_t)b * T_ + t) << 6) + lane] =
                    __float2bfloat16(h);
            xr = xrn;
        }
    }
    __syncthreads();

    // =================== Phase C: fusion + attention (online softmax) =========
    {
        f2 fw[32];
        #pragma unroll
        for (int j = 0; j < 32; ++j) {
            fw[j].x = fu_w[lane * 64 + 2*j];
            fw[j].y = fu_w[lane * 64 + 2*j + 1];
        }
        const float fub = fu_b[lane];
        f2 aw[16];
        #pragma unroll
        for (int j = 0; j < 16; ++j) {
            aw[j].x = at_w1[u * 64 + hb32 + 2*j];
            aw[j].y = at_w1[u * 64 + hb32 + 2*j + 1];
        }
        const float ab1 = at_b1[u];
        const float aw2 = at_w2[u];
        const float ab2 = at_b2[0];
        float m_run = -3.0e38f, s_run = 0.0f, c_run = 0.0f;

        for (int k = 0; k < 128; ++k) {
            const int t = wid + 4 * k;
            f2 acc = {0.f, 0.f};
            if constexpr (sizeof(HT) == 4) {
                const float4* hp = (const float4*)((const float*)hseq +
                                                   (((size_t)b * T_ + t) << 6));
                #pragma unroll
                for (int c = 0; c < 16; ++c) {
                    float4 q = hp[c];
                    acc.x += fw[2*c].x   * q.x;  acc.y += fw[2*c].y   * q.y;
                    acc.x += fw[2*c+1].x * q.z;  acc.y += fw[2*c+1].y * q.w;
                }
            } else {
                const uint4* hp = (const uint4*)((const unsigned short*)hseq +
                                                 (((size_t)b * T_ + t) << 6));
                #pragma unroll
                for (int c = 0; c < 8; ++c) {
                    uint4 q = hp[c];
                    unsigned int uu[4] = {q.x, q.y, q.z, q.w};
                    #pragma unroll
                    for (int kk = 0; kk < 4; ++kk) {
                        unsigned int lo = uu[kk] << 16;
                        unsigned int hi = uu[kk] & 0xffff0000u;
                        acc.x += fw[4*c + kk].x * __int_as_float((int)lo);
                        acc.y += fw[4*c + kk].y * __int_as_float((int)hi);
                    }
                }
            }
            float ltc = fast_tanh(acc.x + acc.y + fub);
            ltcS[wid][lane] = ltc;
            const float4* lp = (const float4*)(&ltcS[wid][hb32]);
            f2 pacc = {0.f, 0.f};
            DOT16PAIR(pacc, aw, lp);
            float p  = pacc.x + pacc.y;
            float px = __shfl_xor(p, 32);
            float a1 = fast_tanh(p + px + ab1);
            float v  = a1 * aw2;
            v += __shfl_xor(v, 1);  v += __shfl_xor(v, 2);
            v += __shfl_xor(v, 4);  v += __shfl_xor(v, 8);
            v += __shfl_xor(v, 16);
            float logit = v + ab2;
            float mn = fmaxf(m_run, logit);
            float e1 = fexp2((m_run - mn) * L2E);
            float pw = fexp2((logit - mn) * L2E);
            s_run = s_run * e1 + pw;
            c_run = c_run * e1 + pw * ltc;
            m_run = mn;
        }
        if (lane == 0) { mM[wid] = m_run; mS[wid] = s_run; }
        mC[wid][lane] = c_run;
    }
    __syncthreads();

    if (wid == 0) {
        float m0 = mM[0], m1 = mM[1], m2 = mM[2], m3 = mM[3];
        float ms = fmaxf(fmaxf(m0, m1), fmaxf(m2, m3));
        float e0 = fexp2((m0 - ms) * L2E), e1 = fexp2((m1 - ms) * L2E);
        float e2 = fexp2((m2 - ms) * L2E), e3 = fexp2((m3 - ms) * L2E);
        float ss = mS[0]*e0 + mS[1]*e1 + mS[2]*e2 + mS[3]*e3;
        float cc = mC[0][lane]*e0 + mC[1][lane]*e1 + mC[2][lane]*e2 + mC[3][lane]*e3;
        ctx_sh[lane] = cc * frcp(ss);
    }
    __syncthreads();

    // =================== heads ===================
    if (wid == 0) {
        float r1 = d_b1[lane];
        #pragma unroll
        for (int c = 0; c < 16; ++c) {
            float4 cq = ((const float4*)ctx_sh)[c];
            float4 wq = ((const float4*)(d_w1 + lane*64))[c];
            r1 += wq.x*cq.x + wq.y*cq.y + wq.z*cq.z + wq.w*cq.w;
        }
        r1 = fmaxf(r1, 0.0f);
        #pragma unroll
        for (int kk = 0; kk < 5; ++kk) {
            float v = d_w2[kk*64 + lane] * r1;
            v += __shfl_xor(v, 1);  v += __shfl_xor(v, 2);
            v += __shfl_xor(v, 4);  v += __shfl_xor(v, 8);
            v += __shfl_xor(v, 16); v += __shfl_xor(v, 32);
            if (lane == 0) out[b*5 + kk] = v + d_b2[kk];
        }
    } else if (wid == 1) {
        float r1 = o_b1[lane];
        #pragma unroll
        for (int c = 0; c < 16; ++c) {
            float4 cq = ((const float4*)ctx_sh)[c];
            float4 wq = ((const float4*)(o_w1 + lane*64))[c];
            r1 += wq.x*cq.x + wq.y*cq.y + wq.z*cq.z + wq.w*cq.w;
        }
        r1 = fmaxf(r1, 0.0f);
        float acc = 0.0f;
        #pragma unroll
        for (int j = 0; j < 32; ++j) {
            float rj = __shfl(r1, hb32 + j);
            acc += o_w2[u*64 + hb32 + j] * rj;
        }
        acc += __shfl_xor(acc, 32);
        float r2 = fmaxf(acc + o_b2[u], 0.0f);
        float v  = o_w3[u] * r2;
        v += __shfl_xor(v, 1);  v += __shfl_xor(v, 2);
        v += __shfl_xor(v, 4);  v += __shfl_xor(v, 8);
        v += __shfl_xor(v, 16);
        if (lane == 0) out[5*B + b] = fast_sigmoid(v + o_b3[0]);
    } else if (wid == 2) {
        float acc = 0.0f;
        #pragma unroll
        for (int c = 0; c < 8; ++c) {
            float4 cq = ((const float4*)(ctx_sh + hb32))[c];
            float4 wq = ((const float4*)(i_w1 + u*64 + hb32))[c];
            acc += wq.x*cq.x + wq.y*cq.y + wq.z*cq.z + wq.w*cq.w;
        }
        acc += __shfl_xor(acc, 32);
        float r1 = fmaxf(acc + i_b1[u], 0.0f);
        float v  = i_w2[u] * r1;
        v += __shfl_xor(v, 1);  v += __shfl_xor(v, 2);
        v += __shfl_xor(v, 4);  v += __shfl_xor(v, 8);
        v += __shfl_xor(v, 16);
        if (lane == 0) out[6*B + b] = fast_sigmoid(v + i_b2[0]);
    }
}

extern "C" void kernel_launch(void* const* d_in, const int* in_sizes, int n_in,
                              void* d_out, int out_size, void* d_ws, size_t ws_size,
                              hipStream_t stream) {
    (void)n_in; (void)out_size;
    const float* X     = (const float*)d_in[0];
    const float* fg_w1 = (const float*)d_in[1];
    const float* fg_b1 = (const float*)d_in[2];
    const float* fg_w2 = (const float*)d_in[3];
    const float* fg_b2 = (const float*)d_in[4];
    const float* fwin  = (const float*)d_in[5];
    const float* fbin  = (const float*)d_in[6];
    const float* fwrec = (const float*)d_in[7];
    const float* swin  = (const float*)d_in[8];
    const float* sbin  = (const float*)d_in[9];
    const float* swrec = (const float*)d_in[10];
    const float* fu_w  = (const float*)d_in[11];
    const float* fu_b  = (const float*)d_in[12];
    const float* at_w1 = (const float*)d_in[13];
    const float* at_b1 = (const float*)d_in[14];
    const float* at_w2 = (const float*)d_in[15];
    const float* at_b2 = (const float*)d_in[16];
    const float* d_w1  = (const float*)d_in[17];
    const float* d_b1  = (const float*)d_in[18];
    const float* d_w2  = (const float*)d_in[19];
    const float* d_b2  = (const float*)d_in[20];
    const float* o_w1  = (const float*)d_in[21];
    const float* o_b1  = (const float*)d_in[22];
    const float* o_w2  = (const float*)d_in[23];
    const float* o_b2  = (const float*)d_in[24];
    const float* o_w3  = (const float*)d_in[25];
    const float* o_b3  = (const float*)d_in[26];
    const float* i_w1  = (const float*)d_in[27];
    const float* i_b1  = (const float*)d_in[28];
    const float* i_w2  = (const float*)d_in[29];
    const float* i_b2  = (const float*)d_in[30];
    float* out = (float*)d_out;

    const int B = in_sizes[0] / (T_ * D_);
    dim3 grid(B), block(256);
    const size_t need_f32 = (size_t)B * T_ * 64 * sizeof(float);
    if (ws_size >= need_f32) {
        hipLaunchKernelGGL(lnn3<float>, grid, block, 0, stream,
            X, fg_w1, fg_b1, fg_w2, fg_b2, fwin, fbin, fwrec, swin, sbin, swrec,
            fu_w, fu_b, at_w1, at_b1, at_w2, at_b2, d_w1, d_b1, d_w2, d_b2,
            o_w1, o_b1, o_w2, o_b2, o_w3, o_b3, i_w1, i_b1, i_w2, i_b2,
            out, (float*)d_ws, B);
    } else {
        hipLaunchKernelGGL(lnn3<__hip_bfloat16>, grid, block, 0, stream,
            X, fg_w1, fg_b1, fg_w2, fg_b2, fwin, fbin, fwrec, swin, sbin, swrec,
            fu_w, fu_b, at_w1, at_b1, at_w2, at_b2, d_w1, d_b1, d_w2, d_b2,
            o_w1, o_b1, o_w2, o_b2, o_w3, o_b3, i_w1, i_b1, i_w2, i_b2,
            out, (__hip_bfloat16*)d_ws, B);
    }
}

// Round 5
// 303.402 us; speedup vs baseline: 2.4034x; 2.4034x over previous
//
#include <hip/hip_runtime.h>

// LNNRegression R5: 4-wave specialized pipeline, GROUPS OF 4 timesteps per
// barrier (131 barriers instead of 512). Roles rotated per block
// (role = (wid+b)&3) to de-alias roles from SIMDs across co-resident blocks.
//   role0: x DMA (4 loads/iter, counted vmcnt(4), dummy tail) + gate -> h1
//   role1: pre_f/pre_s (lag 0 groups, reads x)
//   role2: tau (group i-1) + LTC recurrence (group i-2); h packed f16 to LDS
//   role3: fusion + attention + online softmax (group i-3), f16 dots
// f16 data paths via v_cvt_pkrtz + v_dot2_f32_f16 (fallback if no builtin).
// Weight regs <= 48 per role (R2 lesson: 64-float arrays went to AGPRs).

#define T_  512
#define D_  31
#define NIT 131   // 128 groups + 3 pipeline lag
#define L2E 1.4426950408889634f

typedef decltype(__builtin_amdgcn_cvt_pkrtz(0.0f, 0.0f)) h2;  // <2 x half>
struct f2 { float x, y; };

__device__ __forceinline__ float fexp2(float x){ return __builtin_amdgcn_exp2f(x); }
__device__ __forceinline__ float frcp (float x){ return __builtin_amdgcn_rcpf(x); }
__device__ __forceinline__ float fast_tanh(float x){
    float e = fexp2(x * 2.8853900817779268f);
    return 1.0f - 2.0f * frcp(1.0f + e);
}
__device__ __forceinline__ float fast_sigmoid(float x){
    return frcp(1.0f + fexp2(x * -1.4426950408889634f));
}
__device__ __forceinline__ h2 bch2(unsigned v){ return __builtin_bit_cast(h2, v); }
__device__ __forceinline__ unsigned bcu(h2 v){ return __builtin_bit_cast(unsigned, v); }

#if __has_builtin(__builtin_amdgcn_fdot2)
#define FDOT2(acc, a, b) (acc) = __builtin_amdgcn_fdot2((a), (b), (acc), false)
#else
#define FDOT2(acc, a, b) (acc) += (float)(a)[0]*(float)(b)[0] + (float)(a)[1]*(float)(b)[1]
#endif

#define BAR() do { asm volatile("s_waitcnt lgkmcnt(0)" ::: "memory"); \
                   __builtin_amdgcn_s_barrier();                      \
                   asm volatile("" ::: "memory"); } while (0)

#define DOT16PAIR(accv, warr, q4)                                  \
    do { _Pragma("unroll")                                         \
        for (int c_ = 0; c_ < 8; ++c_) {                           \
            float4 q_ = (q4)[c_];                                  \
            accv.x += (warr)[2*c_].x   * q_.x;                     \
            accv.y += (warr)[2*c_].y   * q_.y;                     \
            accv.x += (warr)[2*c_+1].x * q_.z;                     \
            accv.y += (warr)[2*c_+1].y * q_.w;                     \
        } } while (0)

__launch_bounds__(256, 4)
__global__ void lnn_g4(
    const float* __restrict__ X,
    const float* __restrict__ fg_w1, const float* __restrict__ fg_b1,
    const float* __restrict__ fg_w2, const float* __restrict__ fg_b2,
    const float* __restrict__ fwin,  const float* __restrict__ fbin,
    const float* __restrict__ fwrec,
    const float* __restrict__ swin,  const float* __restrict__ sbin,
    const float* __restrict__ swrec,
    const float* __restrict__ fu_w,  const float* __restrict__ fu_b,
    const float* __restrict__ at_w1, const float* __restrict__ at_b1,
    const float* __restrict__ at_w2, const float* __restrict__ at_b2,
    const float* __restrict__ d_w1,  const float* __restrict__ d_b1,
    const float* __restrict__ d_w2,  const float* __restrict__ d_b2,
    const float* __restrict__ o_w1,  const float* __restrict__ o_b1,
    const float* __restrict__ o_w2,  const float* __restrict__ o_b2,
    const float* __restrict__ o_w3,  const float* __restrict__ o_b3,
    const float* __restrict__ i_w1,  const float* __restrict__ i_b1,
    const float* __restrict__ i_w2,  const float* __restrict__ i_b2,
    float* __restrict__ out, int B)
{
    const int b    = blockIdx.x;
    const int tx   = threadIdx.x;
    const int wid  = tx >> 6;
    const int lane = tx & 63;
    const int u    = lane & 31;
    const int hb32 = lane & 32;
    const int role = (wid + b) & 3;

    __shared__ float    xr_sh [4][4][32];   // x ring (31 + pad)
    __shared__ float    xdm   [32];         // dummy DMA dest (tail)
    __shared__ float    h1_sh [4][4][32];   // gate hidden
    __shared__ float    pre_sh[4][4][64];   // pre_f | pre_s (bias incl.)
    __shared__ unsigned hpk_sh[4][4][32];   // h packed f16x2
    __shared__ unsigned ltcpk [4][32];      // ltc packed f16x2 (per group)
    __shared__ float    ctx_sh[64];

    if (tx < 32) hpk_sh[3][3][tx] = 0u;                 // h_{-1} = 0
    if (tx < 16) xr_sh[tx >> 2][tx & 3][31] = 0.0f;     // pads = 0

    if (role == 0) {
        // ================= role0: x DMA + gate =================
        f2 wg[16];
        const float* g = fg_w1 + u * 62;
        #pragma unroll
        for (int j = 0; j < 16; ++j) {
            if (lane < 32) {
                wg[j].x = g[2*j] + g[31 + 2*j];
                wg[j].y = (2*j + 1 < 31) ? (g[2*j+1] + g[31 + 2*j+1]) : 0.0f;
            } else {
                wg[j].x = g[31 + 2*j];
                wg[j].y = (2*j + 1 < 31) ? g[31 + 2*j+1] : 0.0f;
            }
        }
        const float b1g = (lane < 32) ? fg_b1[u] : 0.0f;
        const unsigned* Xu = (const unsigned*)(X + (size_t)b * T_ * D_ + lane);
        asm volatile("s_waitcnt vmcnt(0)" ::: "memory");   // weights drained

        // prologue: DMA groups 0,1
        #pragma unroll
        for (int gg = 0; gg < 2; ++gg)
            #pragma unroll
            for (int k = 0; k < 4; ++k)
                if (lane < 31)
                    __builtin_amdgcn_global_load_lds(
                        (const __attribute__((address_space(1))) unsigned*)(Xu + (size_t)(4*gg + k) * 31),
                        (__attribute__((address_space(3))) unsigned*)(&xr_sh[gg][k][0]),
                        4, 0, 0);

        float y_prev = 0.0f;
        for (int i = 0; i < NIT; ++i) {
            asm volatile("s_waitcnt vmcnt(4)" ::: "memory");  // group i landed
            BAR();
            {   // DMA group i+2 (dummy-clamped tail keeps vmcnt uniform)
                const int gq = i + 2;
                #pragma unroll
                for (int k = 0; k < 4; ++k) {
                    int tl = 4*gq + k; if (tl > 511) tl = 511;
                    float* dst = (gq <= 127) ? &xr_sh[gq & 3][k][0] : &xdm[0];
                    if (lane < 31)
                        __builtin_amdgcn_global_load_lds(
                            (const __attribute__((address_space(1))) unsigned*)(Xu + (size_t)tl * 31),
                            (__attribute__((address_space(3))) unsigned*)dst,
                            4, 0, 0);
                }
            }
            if (i <= 127) {
                #pragma unroll
                for (int k = 0; k < 4; ++k) {
                    const float4* xq = (const float4*)(&xr_sh[i & 3][k][0]);
                    f2 acc = {0.f, 0.f};
                    DOT16PAIR(acc, wg, xq);
                    float ag = acc.x + acc.y;
                    float yt = __shfl_xor(ag, 32);      // lanes<32 get B.x_t
                    float yc = (i == 0 && k == 0) ? yt : y_prev;
                    y_prev = yt;
                    float gv = fast_tanh(ag - yc + b1g);
                    if (lane < 32) h1_sh[i & 3][k][lane] = gv;
                }
            }
        }
    } else if (role == 1) {
        // ================= role1: pre_f / pre_s =================
        f2 wp[16];
        const float* pw = (lane < 32) ? (fwin + u * 31) : (swin + u * 31);
        #pragma unroll
        for (int j = 0; j < 16; ++j) {
            wp[j].x = pw[2*j];
            wp[j].y = (2*j + 1 < 31) ? pw[2*j+1] : 0.0f;
        }
        const float preb = (lane < 32) ? fbin[u] : sbin[u];

        for (int i = 0; i < NIT; ++i) {
            BAR();
            if (i <= 127) {
                #pragma unroll
                for (int k = 0; k < 4; ++k) {
                    const float4* xq = (const float4*)(&xr_sh[i & 3][k][0]);
                    f2 acc = {0.f, 0.f};
                    DOT16PAIR(acc, wp, xq);
                    pre_sh[i & 3][k][lane] = acc.x + acc.y + preb;
                }
            }
        }
    } else if (role == 2) {
        // ================= role2: tau + LTC recurrence =================
        h2 wr[16];
        const float* rw = (lane < 32) ? (fwrec + u * 32) : (swrec + u * 32);
        #pragma unroll
        for (int j = 0; j < 16; ++j)
            wr[j] = __builtin_amdgcn_cvt_pkrtz(rw[2*j], rw[2*j+1]);
        const float g2  = fg_w2[u];
        const float b2s = fg_b2[0];
        float rtC[4] = {0.2f, 0.2f, 0.2f, 0.2f};
        float rtN[4] = {0.2f, 0.2f, 0.2f, 0.2f};
        float h_st = 0.0f;

        for (int i = 0; i < NIT; ++i) {
            BAR();
            if (i >= 1 && i <= 128) {       // tau for group i-1
                const int sT = (i - 1) & 3;
                #pragma unroll
                for (int k = 0; k < 4; ++k) {
                    float v = h1_sh[sT][k][u] * g2;
                    v += __shfl_xor(v, 1);  v += __shfl_xor(v, 2);
                    v += __shfl_xor(v, 4);  v += __shfl_xor(v, 8);
                    v += __shfl_xor(v, 16);
                    float cs = fast_sigmoid(v + b2s);
                    rtN[k] = frcp(10.0f - 9.99f * cs);
                }
            }
            if (i >= 2 && i <= 129) {       // recurrence for group i-2
                const int gR = i - 2;
                const int sR = gR & 3;
                #pragma unroll
                for (int k = 0; k < 4; ++k) {
                    const int sP = (k == 0) ? ((gR + 3) & 3) : sR;
                    const int kP = (k + 3) & 3;
                    const uint4* hq = (const uint4*)(&hpk_sh[sP][kP][hb32 >> 1]);
                    float aA = 0.f, aB = 0.f;
                    #pragma unroll
                    for (int j = 0; j < 4; ++j) {
                        uint4 q = hq[j];
                        FDOT2(aA, bch2(q.x), wr[4*j+0]);
                        FDOT2(aB, bch2(q.y), wr[4*j+1]);
                        FDOT2(aA, bch2(q.z), wr[4*j+2]);
                        FDOT2(aB, bch2(q.w), wr[4*j+3]);
                    }
                    float upd = fast_tanh(aA + aB + pre_sh[sR][k][lane]);
                    float rt  = (lane < 32) ? rtC[k] : 0.2f;
                    h_st += (upd - h_st) * rt;
                    float hn = __shfl_xor(h_st, 1);
                    h2 pk = (lane & 1) ? __builtin_amdgcn_cvt_pkrtz(hn, h_st)
                                       : __builtin_amdgcn_cvt_pkrtz(h_st, hn);
                    hpk_sh[sR][k][lane >> 1] = bcu(pk);
                }
            }
            rtC[0] = rtN[0]; rtC[1] = rtN[1]; rtC[2] = rtN[2]; rtC[3] = rtN[3];
        }
    } else {
        // ================= role3: fusion + attention + softmax =================
        h2 fw[32];
        #pragma unroll
        for (int j = 0; j < 32; ++j)
            fw[j] = __builtin_amdgcn_cvt_pkrtz(fu_w[lane*64 + 2*j], fu_w[lane*64 + 2*j+1]);
        const float fub = fu_b[lane];
        h2 aw[16];
        #pragma unroll
        for (int j = 0; j < 16; ++j)
            aw[j] = __builtin_amdgcn_cvt_pkrtz(at_w1[u*64 + hb32 + 2*j],
                                               at_w1[u*64 + hb32 + 2*j+1]);
        const float ab1 = at_b1[u];
        const float aw2 = at_w2[u];
        const float ab2 = at_b2[0];
        float m_run = -3.0e38f, s_run = 0.0f, c_run = 0.0f;

        for (int i = 0; i < NIT; ++i) {
            BAR();
            if (i >= 3) {                   // group i-3 (<= 127 automatic)
                const int sF = (i - 3) & 3;
                #pragma unroll
                for (int k = 0; k < 4; ++k) {
                    const uint4* hq = (const uint4*)(&hpk_sh[sF][k][0]);
                    float aA = 0.f, aB = 0.f;
                    #pragma unroll
                    for (int j = 0; j < 8; ++j) {
                        uint4 q = hq[j];
                        FDOT2(aA, bch2(q.x), fw[4*j+0]);
                        FDOT2(aB, bch2(q.y), fw[4*j+1]);
                        FDOT2(aA, bch2(q.z), fw[4*j+2]);
                        FDOT2(aB, bch2(q.w), fw[4*j+3]);
                    }
                    float ltc = fast_tanh(aA + aB + fub);
                    float ln  = __shfl_xor(ltc, 1);
                    h2 pk = (lane & 1) ? __builtin_amdgcn_cvt_pkrtz(ln, ltc)
                                       : __builtin_amdgcn_cvt_pkrtz(ltc, ln);
                    ltcpk[k][lane >> 1] = bcu(pk);
                    const uint4* lq = (const uint4*)(&ltcpk[k][hb32 >> 1]);
                    float pA = 0.f, pB = 0.f;
                    #pragma unroll
                    for (int j = 0; j < 4; ++j) {
                        uint4 q = lq[j];
                        FDOT2(pA, bch2(q.x), aw[4*j+0]);
                        FDOT2(pB, bch2(q.y), aw[4*j+1]);
                        FDOT2(pA, bch2(q.z), aw[4*j+2]);
                        FDOT2(pB, bch2(q.w), aw[4*j+3]);
                    }
                    float p = pA + pB;
                    p += __shfl_xor(p, 32);
                    float a1 = fast_tanh(p + ab1);
                    float v  = a1 * aw2;
                    v += __shfl_xor(v, 1);  v += __shfl_xor(v, 2);
                    v += __shfl_xor(v, 4);  v += __shfl_xor(v, 8);
                    v += __shfl_xor(v, 16);
                    float logit = v + ab2;
                    float mn = fmaxf(m_run, logit);
                    float e1 = fexp2((m_run - mn) * L2E);
                    float pw = fexp2((logit - mn) * L2E);
                    s_run = s_run * e1 + pw;
                    c_run = c_run * e1 + pw * ltc;
                    m_run = mn;
                }
            }
        }
        ctx_sh[lane] = c_run * frcp(s_run);
    }

    __syncthreads();

    // =================== heads (by wid, off hot path) ===================
    if (wid == 0) {
        float r1 = d_b1[lane];
        #pragma unroll
        for (int c = 0; c < 16; ++c) {
            float4 cq = ((const float4*)ctx_sh)[c];
            float4 wq = ((const float4*)(d_w1 + lane*64))[c];
            r1 += wq.x*cq.x + wq.y*cq.y + wq.z*cq.z + wq.w*cq.w;
        }
        r1 = fmaxf(r1, 0.0f);
        #pragma unroll
        for (int kk = 0; kk < 5; ++kk) {
            float v = d_w2[kk*64 + lane] * r1;
            v += __shfl_xor(v, 1);  v += __shfl_xor(v, 2);
            v += __shfl_xor(v, 4);  v += __shfl_xor(v, 8);
            v += __shfl_xor(v, 16); v += __shfl_xor(v, 32);
            if (lane == 0) out[b*5 + kk] = v + d_b2[kk];
        }
    } else if (wid == 1) {
        float r1 = o_b1[lane];
        #pragma unroll
        for (int c = 0; c < 16; ++c) {
            float4 cq = ((const float4*)ctx_sh)[c];
            float4 wq = ((const float4*)(o_w1 + lane*64))[c];
            r1 += wq.x*cq.x + wq.y*cq.y + wq.z*cq.z + wq.w*cq.w;
        }
        r1 = fmaxf(r1, 0.0f);
        float acc = 0.0f;
        #pragma unroll
        for (int j = 0; j < 32; ++j) {
            float rj = __shfl(r1, hb32 + j);
            acc += o_w2[u*64 + hb32 + j] * rj;
        }
        acc += __shfl_xor(acc, 32);
        float r2 = fmaxf(acc + o_b2[u], 0.0f);
        float v  = o_w3[u] * r2;
        v += __shfl_xor(v, 1);  v += __shfl_xor(v, 2);
        v += __shfl_xor(v, 4);  v += __shfl_xor(v, 8);
        v += __shfl_xor(v, 16);
        if (lane == 0) out[5*B + b] = fast_sigmoid(v + o_b3[0]);
    } else if (wid == 2) {
        float acc = 0.0f;
        #pragma unroll
        for (int c = 0; c < 8; ++c) {
            float4 cq = ((const float4*)(ctx_sh + hb32))[c];
            float4 wq = ((const float4*)(i_w1 + u*64 + hb32))[c];
            acc += wq.x*cq.x + wq.y*cq.y + wq.z*cq.z + wq.w*cq.w;
        }
        acc += __shfl_xor(acc, 32);
        float r1 = fmaxf(acc + i_b1[u], 0.0f);
        float v  = i_w2[u] * r1;
        v += __shfl_xor(v, 1);  v += __shfl_xor(v, 2);
        v += __shfl_xor(v, 4);  v += __shfl_xor(v, 8);
        v += __shfl_xor(v, 16);
        if (lane == 0) out[6*B + b] = fast_sigmoid(v + i_b2[0]);
    }
}

extern "C" void kernel_launch(void* const* d_in, const int* in_sizes, int n_in,
                              void* d_out, int out_size, void* d_ws, size_t ws_size,
                              hipStream_t stream) {
    (void)n_in; (void)out_size; (void)d_ws; (void)ws_size;
    const float* X     = (const float*)d_in[0];
    const float* fg_w1 = (const float*)d_in[1];
    const float* fg_b1 = (const float*)d_in[2];
    const float* fg_w2 = (const float*)d_in[3];
    const float* fg_b2 = (const float*)d_in[4];
    const float* fwin  = (const float*)d_in[5];
    const float* fbin  = (const float*)d_in[6];
    const float* fwrec = (const float*)d_in[7];
    const float* swin  = (const float*)d_in[8];
    const float* sbin  = (const float*)d_in[9];
    const float* swrec = (const float*)d_in[10];
    const float* fu_w  = (const float*)d_in[11];
    const float* fu_b  = (const float*)d_in[12];
    const float* at_w1 = (const float*)d_in[13];
    const float* at_b1 = (const float*)d_in[14];
    const float* at_w2 = (const float*)d_in[15];
    const float* at_b2 = (const float*)d_in[16];
    const float* d_w1  = (const float*)d_in[17];
    const float* d_b1  = (const float*)d_in[18];
    const float* d_w2  = (const float*)d_in[19];
    const float* d_b2  = (const float*)d_in[20];
    const float* o_w1  = (const float*)d_in[21];
    const float* o_b1  = (const float*)d_in[22];
    const float* o_w2  = (const float*)d_in[23];
    const float* o_b2  = (const float*)d_in[24];
    const float* o_w3  = (const float*)d_in[25];
    const float* o_b3  = (const float*)d_in[26];
    const float* i_w1  = (const float*)d_in[27];
    const float* i_b1  = (const float*)d_in[28];
    const float* i_w2  = (const float*)d_in[29];
    const float* i_b2  = (const float*)d_in[30];
    float* out = (float*)d_out;

    const int B = in_sizes[0] / (T_ * D_);
    dim3 grid(B), block(256);
    hipLaunchKernelGGL(lnn_g4, grid, block, 0, stream,
        X, fg_w1, fg_b1, fg_w2, fg_b2, fwin, fbin, fwrec, swin, sbin, swrec,
        fu_w, fu_b, at_w1, at_b1, at_w2, at_b2, d_w1, d_b1, d_w2, d_b2,
        o_w1, o_b1, o_w2, o_b2, o_w3, o_b3, i_w1, i_b1, i_w2, i_b2, out, B);
}

// Round 6
// 300.554 us; speedup vs baseline: 2.4262x; 1.0095x over previous
//
#include <hip/hip_runtime.h>

// LNNRegression R6: 4-wave specialized pipeline, GROUPS OF 8 timesteps per
// barrier (67 barriers). Roles rotated per block (role=(wid+b)&3).
//   role0: x DMA (8 loads/iter, counted vmcnt(8), dummy tail) + gate -> h1
//   role1: pre_f/pre_s (group i) + tau reduce (group i-1)  [tau moved here]
//   role2: LTC recurrence only (group i-2); h packed f16 to LDS
//   role3: fusion + attention + STATIC-MAX online softmax (group i-3)
// Static max: |logit| <= ||at_w2||_1 + |b2| ~ 1.3 (a1=tanh in [-1,1]) -> m=0.
// f16 data paths via v_cvt_pkrtz + v_dot2_f32_f16.

#define T_  512
#define D_  31
#define GR_ 8     // steps per group
#define NG_ 64    // groups
#define NIT 67    // 64 groups + 3 pipeline lag
#define L2E 1.4426950408889634f

typedef decltype(__builtin_amdgcn_cvt_pkrtz(0.0f, 0.0f)) h2;  // <2 x half>
struct f2 { float x, y; };

__device__ __forceinline__ float fexp2(float x){ return __builtin_amdgcn_exp2f(x); }
__device__ __forceinline__ float frcp (float x){ return __builtin_amdgcn_rcpf(x); }
__device__ __forceinline__ float fast_tanh(float x){
    float e = fexp2(x * 2.8853900817779268f);
    return 1.0f - 2.0f * frcp(1.0f + e);
}
__device__ __forceinline__ float fast_sigmoid(float x){
    return frcp(1.0f + fexp2(x * -1.4426950408889634f));
}
__device__ __forceinline__ h2 bch2(unsigned v){ return __builtin_bit_cast(h2, v); }
__device__ __forceinline__ unsigned bcu(h2 v){ return __builtin_bit_cast(unsigned, v); }

#if __has_builtin(__builtin_amdgcn_fdot2)
#define FDOT2(acc, a, b) (acc) = __builtin_amdgcn_fdot2((a), (b), (acc), false)
#else
#define FDOT2(acc, a, b) (acc) += (float)(a)[0]*(float)(b)[0] + (float)(a)[1]*(float)(b)[1]
#endif

#define BAR() do { asm volatile("s_waitcnt lgkmcnt(0)" ::: "memory"); \
                   __builtin_amdgcn_s_barrier();                      \
                   asm volatile("" ::: "memory"); } while (0)

#define DOT16PAIR(accv, warr, q4)                                  \
    do { _Pragma("unroll")                                         \
        for (int c_ = 0; c_ < 8; ++c_) {                           \
            float4 q_ = (q4)[c_];                                  \
            accv.x += (warr)[2*c_].x   * q_.x;                     \
            accv.y += (warr)[2*c_].y   * q_.y;                     \
            accv.x += (warr)[2*c_+1].x * q_.z;                     \
            accv.y += (warr)[2*c_+1].y * q_.w;                     \
        } } while (0)

__launch_bounds__(256, 4)
__global__ void lnn_g8(
    const float* __restrict__ X,
    const float* __restrict__ fg_w1, const float* __restrict__ fg_b1,
    const float* __restrict__ fg_w2, const float* __restrict__ fg_b2,
    const float* __restrict__ fwin,  const float* __restrict__ fbin,
    const float* __restrict__ fwrec,
    const float* __restrict__ swin,  const float* __restrict__ sbin,
    const float* __restrict__ swrec,
    const float* __restrict__ fu_w,  const float* __restrict__ fu_b,
    const float* __restrict__ at_w1, const float* __restrict__ at_b1,
    const float* __restrict__ at_w2, const float* __restrict__ at_b2,
    const float* __restrict__ d_w1,  const float* __restrict__ d_b1,
    const float* __restrict__ d_w2,  const float* __restrict__ d_b2,
    const float* __restrict__ o_w1,  const float* __restrict__ o_b1,
    const float* __restrict__ o_w2,  const float* __restrict__ o_b2,
    const float* __restrict__ o_w3,  const float* __restrict__ o_b3,
    const float* __restrict__ i_w1,  const float* __restrict__ i_b1,
    const float* __restrict__ i_w2,  const float* __restrict__ i_b2,
    float* __restrict__ out, int B)
{
    const int b    = blockIdx.x;
    const int tx   = threadIdx.x;
    const int wid  = tx >> 6;
    const int lane = tx & 63;
    const int u    = lane & 31;
    const int hb32 = lane & 32;
    const int role = (wid + b) & 3;

    __shared__ float    xr_sh [4][GR_][32];   // x ring (31 + pad)
    __shared__ float    xdm   [32];           // dummy DMA dest (tail)
    __shared__ float    h1_sh [4][GR_][32];   // gate hidden
    __shared__ float    pre_sh[4][GR_][64];   // pre_f | pre_s (bias incl.)
    __shared__ float    rt_sh [4][GR_];       // 1/tau_fast
    __shared__ unsigned hpk_sh[4][GR_][32];   // h packed f16x2
    __shared__ unsigned ltcpk [GR_][32];      // ltc packed f16x2
    __shared__ float    ctx_sh[64];

    if (tx < 32) hpk_sh[3][GR_-1][tx] = 0u;             // h_{-1} = 0
    if (tx < 32) xr_sh[tx >> 3][tx & 7][31] = 0.0f;     // pads = 0

    if (role == 0) {
        // ================= role0: x DMA + gate =================
        f2 wg[16];
        const float* g = fg_w1 + u * 62;
        #pragma unroll
        for (int j = 0; j < 16; ++j) {
            if (lane < 32) {
                wg[j].x = g[2*j] + g[31 + 2*j];
                wg[j].y = (2*j + 1 < 31) ? (g[2*j+1] + g[31 + 2*j+1]) : 0.0f;
            } else {
                wg[j].x = g[31 + 2*j];
                wg[j].y = (2*j + 1 < 31) ? g[31 + 2*j+1] : 0.0f;
            }
        }
        const float b1g = (lane < 32) ? fg_b1[u] : 0.0f;
        const unsigned* Xu = (const unsigned*)(X + (size_t)b * T_ * D_ + lane);
        asm volatile("s_waitcnt vmcnt(0)" ::: "memory");   // weights drained

        // prologue: DMA groups 0,1 (16 loads)
        #pragma unroll
        for (int gg = 0; gg < 2; ++gg)
            #pragma unroll
            for (int k = 0; k < GR_; ++k)
                if (lane < 31)
                    __builtin_amdgcn_global_load_lds(
                        (const __attribute__((address_space(1))) unsigned*)(Xu + (size_t)(GR_*gg + k) * 31),
                        (__attribute__((address_space(3))) unsigned*)(&xr_sh[gg][k][0]),
                        4, 0, 0);

        float y_prev = 0.0f;
        for (int i = 0; i < NIT; ++i) {
            asm volatile("s_waitcnt vmcnt(8)" ::: "memory");  // group i landed
            BAR();
            {   // DMA group i+2 (dummy-clamped tail keeps vmcnt uniform)
                const int gq = i + 2;
                #pragma unroll
                for (int k = 0; k < GR_; ++k) {
                    int tl = GR_*gq + k; if (tl > 511) tl = 511;
                    float* dst = (gq <= NG_-1) ? &xr_sh[gq & 3][k][0] : &xdm[0];
                    if (lane < 31)
                        __builtin_amdgcn_global_load_lds(
                            (const __attribute__((address_space(1))) unsigned*)(Xu + (size_t)tl * 31),
                            (__attribute__((address_space(3))) unsigned*)dst,
                            4, 0, 0);
                }
            }
            if (i <= NG_-1) {
                #pragma unroll
                for (int k = 0; k < GR_; ++k) {
                    const float4* xq = (const float4*)(&xr_sh[i & 3][k][0]);
                    f2 acc = {0.f, 0.f};
                    DOT16PAIR(acc, wg, xq);
                    float ag = acc.x + acc.y;
                    float yt = __shfl_xor(ag, 32);      // lanes<32 get B.x_t
                    float yc = (i == 0 && k == 0) ? yt : y_prev;
                    y_prev = yt;
                    float gv = fast_tanh(ag - yc + b1g);
                    if (lane < 32) h1_sh[i & 3][k][lane] = gv;
                }
            }
        }
        asm volatile("s_waitcnt vmcnt(0)" ::: "memory");   // drain dummies
    } else if (role == 1) {
        // ================= role1: pre (group i) + tau (group i-1) =========
        f2 wp[16];
        const float* pw = (lane < 32) ? (fwin + u * 31) : (swin + u * 31);
        #pragma unroll
        for (int j = 0; j < 16; ++j) {
            wp[j].x = pw[2*j];
            wp[j].y = (2*j + 1 < 31) ? pw[2*j+1] : 0.0f;
        }
        const float preb = (lane < 32) ? fbin[u] : sbin[u];
        const float g2   = fg_w2[u];
        const float b2s  = fg_b2[0];

        for (int i = 0; i < NIT; ++i) {
            BAR();
            if (i <= NG_-1) {
                #pragma unroll
                for (int k = 0; k < GR_; ++k) {
                    const float4* xq = (const float4*)(&xr_sh[i & 3][k][0]);
                    f2 acc = {0.f, 0.f};
                    DOT16PAIR(acc, wp, xq);
                    pre_sh[i & 3][k][lane] = acc.x + acc.y + preb;
                }
            }
            if (i >= 1 && i <= NG_) {
                const int sT = (i - 1) & 3;
                #pragma unroll
                for (int k = 0; k < GR_; ++k) {
                    float v = h1_sh[sT][k][u] * g2;
                    v += __shfl_xor(v, 1);  v += __shfl_xor(v, 2);
                    v += __shfl_xor(v, 4);  v += __shfl_xor(v, 8);
                    v += __shfl_xor(v, 16);
                    float cs = fast_sigmoid(v + b2s);
                    if (lane == 0) rt_sh[sT][k] = frcp(10.0f - 9.99f * cs);
                }
            }
        }
    } else if (role == 2) {
        // ================= role2: LTC recurrence only =================
        h2 wr[16];
        const float* rw = (lane < 32) ? (fwrec + u * 32) : (swrec + u * 32);
        #pragma unroll
        for (int j = 0; j < 16; ++j)
            wr[j] = __builtin_amdgcn_cvt_pkrtz(rw[2*j], rw[2*j+1]);
        float h_st = 0.0f;

        for (int i = 0; i < NIT; ++i) {
            BAR();
            if (i >= 2 && i <= NG_+1) {
                const int gR = i - 2;
                const int sR = gR & 3;
                #pragma unroll
                for (int k = 0; k < GR_; ++k) {
                    const int sP = (k == 0) ? ((gR + 3) & 3) : sR;
                    const int kP = (k + GR_-1) & (GR_-1);
                    const uint4* hq = (const uint4*)(&hpk_sh[sP][kP][hb32 >> 1]);
                    float aA = 0.f, aB = 0.f;
                    #pragma unroll
                    for (int j = 0; j < 4; ++j) {
                        uint4 q = hq[j];
                        FDOT2(aA, bch2(q.x), wr[4*j+0]);
                        FDOT2(aB, bch2(q.y), wr[4*j+1]);
                        FDOT2(aA, bch2(q.z), wr[4*j+2]);
                        FDOT2(aB, bch2(q.w), wr[4*j+3]);
                    }
                    float upd = fast_tanh(aA + aB + pre_sh[sR][k][lane]);
                    float rt  = (lane < 32) ? rt_sh[sR][k] : 0.2f;
                    h_st += (upd - h_st) * rt;
                    float hn = __shfl_xor(h_st, 1);
                    h2 pk = (lane & 1) ? __builtin_amdgcn_cvt_pkrtz(hn, h_st)
                                       : __builtin_amdgcn_cvt_pkrtz(h_st, hn);
                    hpk_sh[sR][k][lane >> 1] = bcu(pk);
                }
            }
        }
    } else {
        // ========= role3: fusion + attention + static-max softmax =========
        h2 fw[32];
        #pragma unroll
        for (int j = 0; j < 32; ++j)
            fw[j] = __builtin_amdgcn_cvt_pkrtz(fu_w[lane*64 + 2*j], fu_w[lane*64 + 2*j+1]);
        const float fub = fu_b[lane];
        h2 aw[16];
        #pragma unroll
        for (int j = 0; j < 16; ++j)
            aw[j] = __builtin_amdgcn_cvt_pkrtz(at_w1[u*64 + hb32 + 2*j],
                                               at_w1[u*64 + hb32 + 2*j+1]);
        const float ab1 = at_b1[u];
        const float aw2 = at_w2[u];
        const float ab2 = at_b2[0];
        float s_run = 0.0f, c_run = 0.0f;   // static max m=0 (|logit|<~2)

        for (int i = 0; i < NIT; ++i) {
            BAR();
            if (i >= 3) {                   // group i-3 (<= NG_-1 automatic)
                const int sF = (i - 3) & 3;
                #pragma unroll
                for (int k = 0; k < GR_; ++k) {
                    const uint4* hq = (const uint4*)(&hpk_sh[sF][k][0]);
                    float aA = 0.f, aB = 0.f;
                    #pragma unroll
                    for (int j = 0; j < 8; ++j) {
                        uint4 q = hq[j];
                        FDOT2(aA, bch2(q.x), fw[4*j+0]);
                        FDOT2(aB, bch2(q.y), fw[4*j+1]);
                        FDOT2(aA, bch2(q.z), fw[4*j+2]);
                        FDOT2(aB, bch2(q.w), fw[4*j+3]);
                    }
                    float ltc = fast_tanh(aA + aB + fub);
                    float ln  = __shfl_xor(ltc, 1);
                    h2 pk = (lane & 1) ? __builtin_amdgcn_cvt_pkrtz(ln, ltc)
                                       : __builtin_amdgcn_cvt_pkrtz(ltc, ln);
                    ltcpk[k][lane >> 1] = bcu(pk);
                    const uint4* lq = (const uint4*)(&ltcpk[k][hb32 >> 1]);
                    float pA = 0.f, pB = 0.f;
                    #pragma unroll
                    for (int j = 0; j < 4; ++j) {
                        uint4 q = lq[j];
                        FDOT2(pA, bch2(q.x), aw[4*j+0]);
                        FDOT2(pB, bch2(q.y), aw[4*j+1]);
                        FDOT2(pA, bch2(q.z), aw[4*j+2]);
                        FDOT2(pB, bch2(q.w), aw[4*j+3]);
                    }
                    float p = pA + pB;
                    p += __shfl_xor(p, 32);
                    float a1 = fast_tanh(p + ab1);
                    float v  = a1 * aw2;
                    v += __shfl_xor(v, 1);  v += __shfl_xor(v, 2);
                    v += __shfl_xor(v, 4);  v += __shfl_xor(v, 8);
                    v += __shfl_xor(v, 16);
                    float pw = fexp2((v + ab2) * L2E);
                    s_run += pw;
                    c_run += pw * ltc;
                }
            }
        }
        ctx_sh[lane] = c_run * frcp(s_run);
    }

    __syncthreads();

    // =================== heads (by wid, off hot path) ===================
    if (wid == 0) {
        float r1 = d_b1[lane];
        #pragma unroll
        for (int c = 0; c < 16; ++c) {
            float4 cq = ((const float4*)ctx_sh)[c];
            float4 wq = ((const float4*)(d_w1 + lane*64))[c];
            r1 += wq.x*cq.x + wq.y*cq.y + wq.z*cq.z + wq.w*cq.w;
        }
        r1 = fmaxf(r1, 0.0f);
        #pragma unroll
        for (int kk = 0; kk < 5; ++kk) {
            float v = d_w2[kk*64 + lane] * r1;
            v += __shfl_xor(v, 1);  v += __shfl_xor(v, 2);
            v += __shfl_xor(v, 4);  v += __shfl_xor(v, 8);
            v += __shfl_xor(v, 16); v += __shfl_xor(v, 32);
            if (lane == 0) out[b*5 + kk] = v + d_b2[kk];
        }
    } else if (wid == 1) {
        float r1 = o_b1[lane];
        #pragma unroll
        for (int c = 0; c < 16; ++c) {
            float4 cq = ((const float4*)ctx_sh)[c];
            float4 wq = ((const float4*)(o_w1 + lane*64))[c];
            r1 += wq.x*cq.x + wq.y*cq.y + wq.z*cq.z + wq.w*cq.w;
        }
        r1 = fmaxf(r1, 0.0f);
        float acc = 0.0f;
        #pragma unroll
        for (int j = 0; j < 32; ++j) {
            float rj = __shfl(r1, hb32 + j);
            acc += o_w2[u*64 + hb32 + j] * rj;
        }
        acc += __shfl_xor(acc, 32);
        float r2 = fmaxf(acc + o_b2[u], 0.0f);
        float v  = o_w3[u] * r2;
        v += __shfl_xor(v, 1);  v += __shfl_xor(v, 2);
        v += __shfl_xor(v, 4);  v += __shfl_xor(v, 8);
        v += __shfl_xor(v, 16);
        if (lane == 0) out[5*B + b] = fast_sigmoid(v + o_b3[0]);
    } else if (wid == 2) {
        float acc = 0.0f;
        #pragma unroll
        for (int c = 0; c < 8; ++c) {
            float4 cq = ((const float4*)(ctx_sh + hb32))[c];
            float4 wq = ((const float4*)(i_w1 + u*64 + hb32))[c];
            acc += wq.x*cq.x + wq.y*cq.y + wq.z*cq.z + wq.w*cq.w;
        }
        acc += __shfl_xor(acc, 32);
        float r1 = fmaxf(acc + i_b1[u], 0.0f);
        float v  = i_w2[u] * r1;
        v += __shfl_xor(v, 1);  v += __shfl_xor(v, 2);
        v += __shfl_xor(v, 4);  v += __shfl_xor(v, 8);
        v += __shfl_xor(v, 16);
        if (lane == 0) out[6*B + b] = fast_sigmoid(v + i_b2[0]);
    }
}

extern "C" void kernel_launch(void* const* d_in, const int* in_sizes, int n_in,
                              void* d_out, int out_size, void* d_ws, size_t ws_size,
                              hipStream_t stream) {
    (void)n_in; (void)out_size; (void)d_ws; (void)ws_size;
    const float* X     = (const float*)d_in[0];
    const float* fg_w1 = (const float*)d_in[1];
    const float* fg_b1 = (const float*)d_in[2];
    const float* fg_w2 = (const float*)d_in[3];
    const float* fg_b2 = (const float*)d_in[4];
    const float* fwin  = (const float*)d_in[5];
    const float* fbin  = (const float*)d_in[6];
    const float* fwrec = (const float*)d_in[7];
    const float* swin  = (const float*)d_in[8];
    const float* sbin  = (const float*)d_in[9];
    const float* swrec = (const float*)d_in[10];
    const float* fu_w  = (const float*)d_in[11];
    const float* fu_b  = (const float*)d_in[12];
    const float* at_w1 = (const float*)d_in[13];
    const float* at_b1 = (const float*)d_in[14];
    const float* at_w2 = (const float*)d_in[15];
    const float* at_b2 = (const float*)d_in[16];
    const float* d_w1  = (const float*)d_in[17];
    const float* d_b1  = (const float*)d_in[18];
    const float* d_w2  = (const float*)d_in[19];
    const float* d_b2  = (const float*)d_in[20];
    const float* o_w1  = (const float*)d_in[21];
    const float* o_b1  = (const float*)d_in[22];
    const float* o_w2  = (const float*)d_in[23];
    const float* o_b2  = (const float*)d_in[24];
    const float* o_w3  = (const float*)d_in[25];
    const float* o_b3  = (const float*)d_in[26];
    const float* i_w1  = (const float*)d_in[27];
    const float* i_b1  = (const float*)d_in[28];
    const float* i_w2  = (const float*)d_in[29];
    const float* i_b2  = (const float*)d_in[30];
    float* out = (float*)d_out;

    const int B = in_sizes[0] / (T_ * D_);
    dim3 grid(B), block(256);
    hipLaunchKernelGGL(lnn_g8, grid, block, 0, stream,
        X, fg_w1, fg_b1, fg_w2, fg_b2, fwin, fbin, fwrec, swin, sbin, swrec,
        fu_w, fu_b, at_w1, at_b1, at_w2, at_b2, d_w1, d_b1, d_w2, d_b2,
        o_w1, o_b1, o_w2, o_b2, o_w3, o_b3, i_w1, i_b1, i_w2, i_b2, out, B);
}

// Round 8
// 260.153 us; speedup vs baseline: 2.8030x; 1.1553x over previous
//
#include <hip/hip_runtime.h>

// LNNRegression R8 (= R7 with DPP ctrl as template constant):
// R6 structure (4-wave pipeline, 8-step groups, 67 barriers) + issue surgery:
//   - v_pk_fma_f32 (ext_vector float2) for role0/role1 f32 dots
//   - DPP butterfly (quad_perm/mirror) + 1 ds_swizzle for 32-lane reductions
//   - xor-1 pack shuffles via DPP quad_perm
//   - L2E folded into tau/attention scalar weights

#define T_  512
#define D_  31
#define GR_ 8     // steps per group
#define NG_ 64    // groups
#define NIT 67    // 64 groups + 3 pipeline lag
#define L2E 1.4426950408889634f

typedef decltype(__builtin_amdgcn_cvt_pkrtz(0.0f, 0.0f)) h2;  // <2 x half>
typedef float v2f __attribute__((ext_vector_type(2)));

__device__ __forceinline__ float fexp2(float x){ return __builtin_amdgcn_exp2f(x); }
__device__ __forceinline__ float frcp (float x){ return __builtin_amdgcn_rcpf(x); }
__device__ __forceinline__ float fast_tanh(float x){
    float e = fexp2(x * 2.8853900817779268f);
    return 1.0f - 2.0f * frcp(1.0f + e);
}
__device__ __forceinline__ h2 bch2(unsigned v){ return __builtin_bit_cast(h2, v); }
__device__ __forceinline__ unsigned bcu(h2 v){ return __builtin_bit_cast(unsigned, v); }

// DPP-permuted copy (full-rate VALU, no LDS pipe). CTRL must be constexpr.
template <int CTRL>
__device__ __forceinline__ float dppf(float v){
    int r = __builtin_amdgcn_update_dpp(0, __builtin_bit_cast(int, v),
                                        CTRL, 0xf, 0xf, true);
    return __builtin_bit_cast(float, r);
}
// sum over each 32-lane half, result in all lanes of the half
__device__ __forceinline__ float rsum32(float v){
    v += dppf<0xB1>(v);    // quad_perm [1,0,3,2]  : xor 1
    v += dppf<0x4E>(v);    // quad_perm [2,3,0,1]  : xor 2
    v += dppf<0x141>(v);   // row_half_mirror      : cross-quad in 8
    v += dppf<0x140>(v);   // row_mirror           : cross-8 in 16
    v += __builtin_bit_cast(float,
         __builtin_amdgcn_ds_swizzle(__builtin_bit_cast(int, v), 0x401F)); // xor16
    return v;
}

#if __has_builtin(__builtin_amdgcn_fdot2)
#define FDOT2(acc, a, b) (acc) = __builtin_amdgcn_fdot2((a), (b), (acc), false)
#else
#define FDOT2(acc, a, b) (acc) += (float)(a)[0]*(float)(b)[0] + (float)(a)[1]*(float)(b)[1]
#endif

#define BAR() do { asm volatile("s_waitcnt lgkmcnt(0)" ::: "memory"); \
                   __builtin_amdgcn_s_barrier();                      \
                   asm volatile("" ::: "memory"); } while (0)

// acc (v2f) += w[16] (v2f, packed pairs) dot 32-float vector read as 8x float4
#define DOTPK(acc, warr, q4)                                       \
    do { _Pragma("unroll")                                         \
        for (int c_ = 0; c_ < 8; ++c_) {                           \
            float4 q_ = (q4)[c_];                                  \
            v2f lo_; lo_.x = q_.x; lo_.y = q_.y;                   \
            v2f hi_; hi_.x = q_.z; hi_.y = q_.w;                   \
            acc += (warr)[2*c_]   * lo_;                           \
            acc += (warr)[2*c_+1] * hi_;                           \
        } } while (0)

__launch_bounds__(256, 4)
__global__ void lnn_g8(
    const float* __restrict__ X,
    const float* __restrict__ fg_w1, const float* __restrict__ fg_b1,
    const float* __restrict__ fg_w2, const float* __restrict__ fg_b2,
    const float* __restrict__ fwin,  const float* __restrict__ fbin,
    const float* __restrict__ fwrec,
    const float* __restrict__ swin,  const float* __restrict__ sbin,
    const float* __restrict__ swrec,
    const float* __restrict__ fu_w,  const float* __restrict__ fu_b,
    const float* __restrict__ at_w1, const float* __restrict__ at_b1,
    const float* __restrict__ at_w2, const float* __restrict__ at_b2,
    const float* __restrict__ d_w1,  const float* __restrict__ d_b1,
    const float* __restrict__ d_w2,  const float* __restrict__ d_b2,
    const float* __restrict__ o_w1,  const float* __restrict__ o_b1,
    const float* __restrict__ o_w2,  const float* __restrict__ o_b2,
    const float* __restrict__ o_w3,  const float* __restrict__ o_b3,
    const float* __restrict__ i_w1,  const float* __restrict__ i_b1,
    const float* __restrict__ i_w2,  const float* __restrict__ i_b2,
    float* __restrict__ out, int B)
{
    const int b    = blockIdx.x;
    const int tx   = threadIdx.x;
    const int wid  = tx >> 6;
    const int lane = tx & 63;
    const int u    = lane & 31;
    const int hb32 = lane & 32;
    const int role = (wid + b) & 3;

    __shared__ float    xr_sh [4][GR_][32];   // x ring (31 + pad)
    __shared__ float    xdm   [32];           // dummy DMA dest (tail)
    __shared__ float    h1_sh [4][GR_][32];   // gate hidden
    __shared__ float    pre_sh[4][GR_][64];   // pre_f | pre_s (bias incl.)
    __shared__ float    rt_sh [4][GR_];       // 1/tau_fast
    __shared__ unsigned hpk_sh[4][GR_][32];   // h packed f16x2
    __shared__ unsigned ltcpk [GR_][32];      // ltc packed f16x2
    __shared__ float    ctx_sh[64];

    if (tx < 32) hpk_sh[3][GR_-1][tx] = 0u;             // h_{-1} = 0
    if (tx < 32) xr_sh[tx >> 3][tx & 7][31] = 0.0f;     // pads = 0

    if (role == 0) {
        // ================= role0: x DMA + gate =================
        v2f wg[16];
        const float* g = fg_w1 + u * 62;
        #pragma unroll
        for (int j = 0; j < 16; ++j) {
            if (lane < 32) {
                wg[j].x = g[2*j] + g[31 + 2*j];
                wg[j].y = (2*j + 1 < 31) ? (g[2*j+1] + g[31 + 2*j+1]) : 0.0f;
            } else {
                wg[j].x = g[31 + 2*j];
                wg[j].y = (2*j + 1 < 31) ? g[31 + 2*j+1] : 0.0f;
            }
        }
        const float b1g = (lane < 32) ? fg_b1[u] : 0.0f;
        const unsigned* Xu = (const unsigned*)(X + (size_t)b * T_ * D_ + lane);
        asm volatile("s_waitcnt vmcnt(0)" ::: "memory");   // weights drained

        // prologue: DMA groups 0,1 (16 loads)
        #pragma unroll
        for (int gg = 0; gg < 2; ++gg)
            #pragma unroll
            for (int k = 0; k < GR_; ++k)
                if (lane < 31)
                    __builtin_amdgcn_global_load_lds(
                        (const __attribute__((address_space(1))) unsigned*)(Xu + (size_t)(GR_*gg + k) * 31),
                        (__attribute__((address_space(3))) unsigned*)(&xr_sh[gg][k][0]),
                        4, 0, 0);

        float y_prev = 0.0f;
        for (int i = 0; i < NIT; ++i) {
            asm volatile("s_waitcnt vmcnt(8)" ::: "memory");  // group i landed
            BAR();
            {   // DMA group i+2 (dummy-clamped tail keeps vmcnt uniform)
                const int gq = i + 2;
                #pragma unroll
                for (int k = 0; k < GR_; ++k) {
                    int tl = GR_*gq + k; if (tl > 511) tl = 511;
                    float* dst = (gq <= NG_-1) ? &xr_sh[gq & 3][k][0] : &xdm[0];
                    if (lane < 31)
                        __builtin_amdgcn_global_load_lds(
                            (const __attribute__((address_space(1))) unsigned*)(Xu + (size_t)tl * 31),
                            (__attribute__((address_space(3))) unsigned*)dst,
                            4, 0, 0);
                }
            }
            if (i <= NG_-1) {
                #pragma unroll
                for (int k = 0; k < GR_; ++k) {
                    const float4* xq = (const float4*)(&xr_sh[i & 3][k][0]);
                    v2f acc = {0.f, 0.f};
                    DOTPK(acc, wg, xq);
                    float ag = acc.x + acc.y;
                    float yt = __shfl_xor(ag, 32);      // lanes<32 get B.x_t
                    float yc = (i == 0 && k == 0) ? yt : y_prev;
                    y_prev = yt;
                    float gv = fast_tanh(ag - yc + b1g);
                    if (lane < 32) h1_sh[i & 3][k][lane] = gv;
                }
            }
        }
        asm volatile("s_waitcnt vmcnt(0)" ::: "memory");   // drain dummies
    } else if (role == 1) {
        // ================= role1: pre (group i) + tau (group i-1) =========
        v2f wp[16];
        const float* pw = (lane < 32) ? (fwin + u * 31) : (swin + u * 31);
        #pragma unroll
        for (int j = 0; j < 16; ++j) {
            wp[j].x = pw[2*j];
            wp[j].y = (2*j + 1 < 31) ? pw[2*j+1] : 0.0f;
        }
        const float preb = (lane < 32) ? fbin[u] : sbin[u];
        const float g2m  = fg_w2[u] * (-L2E);   // fold -L2E into sigmoid
        const float b2m  = fg_b2[0] * (-L2E);

        for (int i = 0; i < NIT; ++i) {
            BAR();
            if (i <= NG_-1) {
                #pragma unroll
                for (int k = 0; k < GR_; ++k) {
                    const float4* xq = (const float4*)(&xr_sh[i & 3][k][0]);
                    v2f acc = {0.f, 0.f};
                    DOTPK(acc, wp, xq);
                    pre_sh[i & 3][k][lane] = acc.x + acc.y + preb;
                }
            }
            if (i >= 1 && i <= NG_) {
                const int sT = (i - 1) & 3;
                #pragma unroll
                for (int k = 0; k < GR_; ++k) {
                    float v = rsum32(h1_sh[sT][k][u] * g2m);
                    float cs = frcp(1.0f + fexp2(v + b2m));
                    if (lane == 0) rt_sh[sT][k] = frcp(10.0f - 9.99f * cs);
                }
            }
        }
    } else if (role == 2) {
        // ================= role2: LTC recurrence only =================
        h2 wr[16];
        const float* rw = (lane < 32) ? (fwrec + u * 32) : (swrec + u * 32);
        #pragma unroll
        for (int j = 0; j < 16; ++j)
            wr[j] = __builtin_amdgcn_cvt_pkrtz(rw[2*j], rw[2*j+1]);
        float h_st = 0.0f;

        for (int i = 0; i < NIT; ++i) {
            BAR();
            if (i >= 2 && i <= NG_+1) {
                const int gR = i - 2;
                const int sR = gR & 3;
                #pragma unroll
                for (int k = 0; k < GR_; ++k) {
                    const int sP = (k == 0) ? ((gR + 3) & 3) : sR;
                    const int kP = (k + GR_-1) & (GR_-1);
                    const uint4* hq = (const uint4*)(&hpk_sh[sP][kP][hb32 >> 1]);
                    float aA = 0.f, aB = 0.f;
                    #pragma unroll
                    for (int j = 0; j < 4; ++j) {
                        uint4 q = hq[j];
                        FDOT2(aA, bch2(q.x), wr[4*j+0]);
                        FDOT2(aB, bch2(q.y), wr[4*j+1]);
                        FDOT2(aA, bch2(q.z), wr[4*j+2]);
                        FDOT2(aB, bch2(q.w), wr[4*j+3]);
                    }
                    float upd = fast_tanh(aA + aB + pre_sh[sR][k][lane]);
                    float rt  = (lane < 32) ? rt_sh[sR][k] : 0.2f;
                    h_st += (upd - h_st) * rt;
                    float hn = dppf<0xB1>(h_st);        // xor-1 neighbor
                    h2 pk = (lane & 1) ? __builtin_amdgcn_cvt_pkrtz(hn, h_st)
                                       : __builtin_amdgcn_cvt_pkrtz(h_st, hn);
                    hpk_sh[sR][k][lane >> 1] = bcu(pk);
                }
            }
        }
    } else {
        // ========= role3: fusion + attention + static-max softmax =========
        h2 fw[32];
        #pragma unroll
        for (int j = 0; j < 32; ++j)
            fw[j] = __builtin_amdgcn_cvt_pkrtz(fu_w[lane*64 + 2*j], fu_w[lane*64 + 2*j+1]);
        const float fub = fu_b[lane];
        h2 aw[16];
        #pragma unroll
        for (int j = 0; j < 16; ++j)
            aw[j] = __builtin_amdgcn_cvt_pkrtz(at_w1[u*64 + hb32 + 2*j],
                                               at_w1[u*64 + hb32 + 2*j+1]);
        const float ab1  = at_b1[u];
        const float aw2L = at_w2[u] * L2E;      // fold L2E into exp path
        const float ab2L = at_b2[0] * L2E;
        float s_run = 0.0f, c_run = 0.0f;       // static max m=0 (|logit|<~2)

        for (int i = 0; i < NIT; ++i) {
            BAR();
            if (i >= 3) {                   // group i-3 (<= NG_-1 automatic)
                const int sF = (i - 3) & 3;
                #pragma unroll
                for (int k = 0; k < GR_; ++k) {
                    const uint4* hq = (const uint4*)(&hpk_sh[sF][k][0]);
                    float aA = 0.f, aB = 0.f;
                    #pragma unroll
                    for (int j = 0; j < 8; ++j) {
                        uint4 q = hq[j];
                        FDOT2(aA, bch2(q.x), fw[4*j+0]);
                        FDOT2(aB, bch2(q.y), fw[4*j+1]);
                        FDOT2(aA, bch2(q.z), fw[4*j+2]);
                        FDOT2(aB, bch2(q.w), fw[4*j+3]);
                    }
                    float ltc = fast_tanh(aA + aB + fub);
                    float ln  = dppf<0xB1>(ltc);        // xor-1 neighbor
                    h2 pk = (lane & 1) ? __builtin_amdgcn_cvt_pkrtz(ln, ltc)
                                       : __builtin_amdgcn_cvt_pkrtz(ltc, ln);
                    ltcpk[k][lane >> 1] = bcu(pk);
                    const uint4* lq = (const uint4*)(&ltcpk[k][hb32 >> 1]);
                    float pA = 0.f, pB = 0.f;
                    #pragma unroll
                    for (int j = 0; j < 4; ++j) {
                        uint4 q = lq[j];
                        FDOT2(pA, bch2(q.x), aw[4*j+0]);
                        FDOT2(pB, bch2(q.y), aw[4*j+1]);
                        FDOT2(pA, bch2(q.z), aw[4*j+2]);
                        FDOT2(pB, bch2(q.w), aw[4*j+3]);
                    }
                    float p = pA + pB;
                    p += __shfl_xor(p, 32);
                    float a1 = fast_tanh(p + ab1);
                    float v  = rsum32(a1 * aw2L);
                    float pw = fexp2(v + ab2L);
                    s_run += pw;
                    c_run += pw * ltc;
                }
            }
        }
        ctx_sh[lane] = c_run * frcp(s_run);
    }

    __syncthreads();

    // =================== heads (by wid, off hot path) ===================
    if (wid == 0) {
        float r1 = d_b1[lane];
        #pragma unroll
        for (int c = 0; c < 16; ++c) {
            float4 cq = ((const float4*)ctx_sh)[c];
            float4 wq = ((const float4*)(d_w1 + lane*64))[c];
            r1 += wq.x*cq.x + wq.y*cq.y + wq.z*cq.z + wq.w*cq.w;
        }
        r1 = fmaxf(r1, 0.0f);
        #pragma unroll
        for (int kk = 0; kk < 5; ++kk) {
            float v = d_w2[kk*64 + lane] * r1;
            v += __shfl_xor(v, 1);  v += __shfl_xor(v, 2);
            v += __shfl_xor(v, 4);  v += __shfl_xor(v, 8);
            v += __shfl_xor(v, 16); v += __shfl_xor(v, 32);
            if (lane == 0) out[b*5 + kk] = v + d_b2[kk];
        }
    } else if (wid == 1) {
        float r1 = o_b1[lane];
        #pragma unroll
        for (int c = 0; c < 16; ++c) {
            float4 cq = ((const float4*)ctx_sh)[c];
            float4 wq = ((const float4*)(o_w1 + lane*64))[c];
            r1 += wq.x*cq.x + wq.y*cq.y + wq.z*cq.z + wq.w*cq.w;
        }
        r1 = fmaxf(r1, 0.0f);
        float acc = 0.0f;
        #pragma unroll
        for (int j = 0; j < 32; ++j) {
            float rj = __shfl(r1, hb32 + j);
            acc += o_w2[u*64 + hb32 + j] * rj;
        }
        acc += __shfl_xor(acc, 32);
        float r2 = fmaxf(acc + o_b2[u], 0.0f);
        float v  = o_w3[u] * r2;
        v += __shfl_xor(v, 1);  v += __shfl_xor(v, 2);
        v += __shfl_xor(v, 4);  v += __shfl_xor(v, 8);
        v += __shfl_xor(v, 16);
        if (lane == 0) {
            float e = fexp2((v + o_b3[0]) * -L2E);
            out[5*B + b] = frcp(1.0f + e);
        }
    } else if (wid == 2) {
        float acc = 0.0f;
        #pragma unroll
        for (int c = 0; c < 8; ++c) {
            float4 cq = ((const float4*)(ctx_sh + hb32))[c];
            float4 wq = ((const float4*)(i_w1 + u*64 + hb32))[c];
            acc += wq.x*cq.x + wq.y*cq.y + wq.z*cq.z + wq.w*cq.w;
        }
        acc += __shfl_xor(acc, 32);
        float r1 = fmaxf(acc + i_b1[u], 0.0f);
        float v  = i_w2[u] * r1;
        v += __shfl_xor(v, 1);  v += __shfl_xor(v, 2);
        v += __shfl_xor(v, 4);  v += __shfl_xor(v, 8);
        v += __shfl_xor(v, 16);
        if (lane == 0) {
            float e = fexp2((v + i_b2[0]) * -L2E);
            out[6*B + b] = frcp(1.0f + e);
        }
    }
}

extern "C" void kernel_launch(void* const* d_in, const int* in_sizes, int n_in,
                              void* d_out, int out_size, void* d_ws, size_t ws_size,
                              hipStream_t stream) {
    (void)n_in; (void)out_size; (void)d_ws; (void)ws_size;
    const float* X     = (const float*)d_in[0];
    const float* fg_w1 = (const float*)d_in[1];
    const float* fg_b1 = (const float*)d_in[2];
    const float* fg_w2 = (const float*)d_in[3];
    const float* fg_b2 = (const float*)d_in[4];
    const float* fwin  = (const float*)d_in[5];
    const float* fbin  = (const float*)d_in[6];
    const float* fwrec = (const float*)d_in[7];
    const float* swin  = (const float*)d_in[8];
    const float* sbin  = (const float*)d_in[9];
    const float* swrec = (const float*)d_in[10];
    const float* fu_w  = (const float*)d_in[11];
    const float* fu_b  = (const float*)d_in[12];
    const float* at_w1 = (const float*)d_in[13];
    const float* at_b1 = (const float*)d_in[14];
    const float* at_w2 = (const float*)d_in[15];
    const float* at_b2 = (const float*)d_in[16];
    const float* d_w1  = (const float*)d_in[17];
    const float* d_b1  = (const float*)d_in[18];
    const float* d_w2  = (const float*)d_in[19];
    const float* d_b2  = (const float*)d_in[20];
    const float* o_w1  = (const float*)d_in[21];
    const float* o_b1  = (const float*)d_in[22];
    const float* o_w2  = (const float*)d_in[23];
    const float* o_b2  = (const float*)d_in[24];
    const float* o_w3  = (const float*)d_in[25];
    const float* o_b3  = (const float*)d_in[26];
    const float* i_w1  = (const float*)d_in[27];
    const float* i_b1  = (const float*)d_in[28];
    const float* i_w2  = (const float*)d_in[29];
    const float* i_b2  = (const float*)d_in[30];
    float* out = (float*)d_out;

    const int B = in_sizes[0] / (T_ * D_);
    dim3 grid(B), block(256);
    hipLaunchKernelGGL(lnn_g8, grid, block, 0, stream,
        X, fg_w1, fg_b1, fg_w2, fg_b2, fwin, fbin, fwrec, swin, sbin, swrec,
        fu_w, fu_b, at_w1, at_b1, at_w2, at_b2, d_w1, d_b1, d_w2, d_b2,
        o_w1, o_b1, o_w2, o_b2, o_w3, o_b3, i_w1, i_b1, i_w2, i_b2, out, B);
}

// Round 9
// 244.365 us; speedup vs baseline: 2.9841x; 1.0646x over previous
//
#include <hip/hip_runtime.h>

// LNNRegression R9: role re-partition of R8 (4 waves, 8-step groups, 67 barriers).
//   role0: x DMA + gate + pre (ONE set of x reads feeds both dots)
//   role1: tau + LTC recurrence FUSED (tau consumed in-register, no rt_sh)
//   role2: fusion (64->64 f16 dot) -> ltcpk ring[2]
//   role3: attention + static-max softmax (own-lane ltc via ds_read_u16)
// Lags: gate/pre i, tau+rec i-1, fusion i-2, attn i-3. NIT=67.

#define T_  512
#define D_  31
#define GR_ 8     // steps per group
#define NG_ 64    // groups
#define NIT 67    // 64 groups + 3 pipeline lag
#define L2E 1.4426950408889634f

typedef decltype(__builtin_amdgcn_cvt_pkrtz(0.0f, 0.0f)) h2;  // <2 x half>
typedef float v2f __attribute__((ext_vector_type(2)));

__device__ __forceinline__ float fexp2(float x){ return __builtin_amdgcn_exp2f(x); }
__device__ __forceinline__ float frcp (float x){ return __builtin_amdgcn_rcpf(x); }
__device__ __forceinline__ float fast_tanh(float x){
    float e = fexp2(x * 2.8853900817779268f);
    return 1.0f - 2.0f * frcp(1.0f + e);
}
__device__ __forceinline__ h2 bch2(unsigned v){ return __builtin_bit_cast(h2, v); }
__device__ __forceinline__ unsigned bcu(h2 v){ return __builtin_bit_cast(unsigned, v); }

template <int CTRL>
__device__ __forceinline__ float dppf(float v){
    int r = __builtin_amdgcn_update_dpp(0, __builtin_bit_cast(int, v),
                                        CTRL, 0xf, 0xf, true);
    return __builtin_bit_cast(float, r);
}
// sum over each 32-lane half, result in all lanes of the half
__device__ __forceinline__ float rsum32(float v){
    v += dppf<0xB1>(v);    // xor 1
    v += dppf<0x4E>(v);    // xor 2
    v += dppf<0x141>(v);   // row_half_mirror
    v += dppf<0x140>(v);   // row_mirror
    v += __builtin_bit_cast(float,
         __builtin_amdgcn_ds_swizzle(__builtin_bit_cast(int, v), 0x401F)); // xor16
    return v;
}

#if __has_builtin(__builtin_amdgcn_fdot2)
#define FDOT2(acc, a, b) (acc) = __builtin_amdgcn_fdot2((a), (b), (acc), false)
#else
#define FDOT2(acc, a, b) (acc) += (float)(a)[0]*(float)(b)[0] + (float)(a)[1]*(float)(b)[1]
#endif

#define BAR() do { asm volatile("s_waitcnt lgkmcnt(0)" ::: "memory"); \
                   __builtin_amdgcn_s_barrier();                      \
                   asm volatile("" ::: "memory"); } while (0)

__launch_bounds__(256, 4)
__global__ void lnn_g8(
    const float* __restrict__ X,
    const float* __restrict__ fg_w1, const float* __restrict__ fg_b1,
    const float* __restrict__ fg_w2, const float* __restrict__ fg_b2,
    const float* __restrict__ fwin,  const float* __restrict__ fbin,
    const float* __restrict__ fwrec,
    const float* __restrict__ swin,  const float* __restrict__ sbin,
    const float* __restrict__ swrec,
    const float* __restrict__ fu_w,  const float* __restrict__ fu_b,
    const float* __restrict__ at_w1, const float* __restrict__ at_b1,
    const float* __restrict__ at_w2, const float* __restrict__ at_b2,
    const float* __restrict__ d_w1,  const float* __restrict__ d_b1,
    const float* __restrict__ d_w2,  const float* __restrict__ d_b2,
    const float* __restrict__ o_w1,  const float* __restrict__ o_b1,
    const float* __restrict__ o_w2,  const float* __restrict__ o_b2,
    const float* __restrict__ o_w3,  const float* __restrict__ o_b3,
    const float* __restrict__ i_w1,  const float* __restrict__ i_b1,
    const float* __restrict__ i_w2,  const float* __restrict__ i_b2,
    float* __restrict__ out, int B)
{
    const int b    = blockIdx.x;
    const int tx   = threadIdx.x;
    const int wid  = tx >> 6;
    const int lane = tx & 63;
    const int u    = lane & 31;
    const int hb32 = lane & 32;
    const int role = (wid + b) & 3;

    __shared__ float    xr_sh [4][GR_][32];   // x ring (31 + pad)
    __shared__ float    xdm   [32];           // dummy DMA dest (tail)
    __shared__ float    h1_sh [4][GR_][32];   // gate hidden
    __shared__ float    pre_sh[4][GR_][64];   // pre_f | pre_s (bias incl.)
    __shared__ unsigned hpk_sh[4][GR_][32];   // h packed f16x2
    __shared__ unsigned ltcpk [2][GR_][32];   // ltc packed f16x2 (ring 2)
    __shared__ float    ctx_sh[64];

    if (tx < 32) hpk_sh[3][GR_-1][tx] = 0u;             // h_{-1} = 0
    if (tx < 32) xr_sh[tx >> 3][tx & 7][31] = 0.0f;     // pads = 0

    if (role == 0) {
        // ========== role0: x DMA + gate + pre (shared x reads) ==========
        v2f wg[16], wp[16];
        {
            const float* g = fg_w1 + u * 62;
            const float* pw = (lane < 32) ? (fwin + u * 31) : (swin + u * 31);
            #pragma unroll
            for (int j = 0; j < 16; ++j) {
                if (lane < 32) {
                    wg[j].x = g[2*j] + g[31 + 2*j];
                    wg[j].y = (2*j + 1 < 31) ? (g[2*j+1] + g[31 + 2*j+1]) : 0.0f;
                } else {
                    wg[j].x = g[31 + 2*j];
                    wg[j].y = (2*j + 1 < 31) ? g[31 + 2*j+1] : 0.0f;
                }
                wp[j].x = pw[2*j];
                wp[j].y = (2*j + 1 < 31) ? pw[2*j+1] : 0.0f;
            }
        }
        const float b1g  = (lane < 32) ? fg_b1[u] : 0.0f;
        const float preb = (lane < 32) ? fbin[u] : sbin[u];
        const unsigned* Xu = (const unsigned*)(X + (size_t)b * T_ * D_ + lane);
        asm volatile("s_waitcnt vmcnt(0)" ::: "memory");   // weights drained

        // prologue: DMA groups 0,1 (16 loads)
        #pragma unroll
        for (int gg = 0; gg < 2; ++gg)
            #pragma unroll
            for (int k = 0; k < GR_; ++k)
                if (lane < 31)
                    __builtin_amdgcn_global_load_lds(
                        (const __attribute__((address_space(1))) unsigned*)(Xu + (size_t)(GR_*gg + k) * 31),
                        (__attribute__((address_space(3))) unsigned*)(&xr_sh[gg][k][0]),
                        4, 0, 0);

        float y_prev = 0.0f;
        for (int i = 0; i < NIT; ++i) {
            asm volatile("s_waitcnt vmcnt(8)" ::: "memory");  // group i landed
            BAR();
            {   // DMA group i+2 (dummy-clamped tail keeps vmcnt uniform)
                const int gq = i + 2;
                #pragma unroll
                for (int k = 0; k < GR_; ++k) {
                    int tl = GR_*gq + k; if (tl > 511) tl = 511;
                    float* dst = (gq <= NG_-1) ? &xr_sh[gq & 3][k][0] : &xdm[0];
                    if (lane < 31)
                        __builtin_amdgcn_global_load_lds(
                            (const __attribute__((address_space(1))) unsigned*)(Xu + (size_t)tl * 31),
                            (__attribute__((address_space(3))) unsigned*)dst,
                            4, 0, 0);
                }
            }
            if (i <= NG_-1) {
                #pragma unroll
                for (int k = 0; k < GR_; ++k) {
                    const float4* xq = (const float4*)(&xr_sh[i & 3][k][0]);
                    v2f ga = {0.f, 0.f}, pa = {0.f, 0.f};
                    #pragma unroll
                    for (int c = 0; c < 8; ++c) {
                        float4 q = xq[c];
                        v2f lo; lo.x = q.x; lo.y = q.y;
                        v2f hi; hi.x = q.z; hi.y = q.w;
                        ga += wg[2*c]   * lo;  pa += wp[2*c]   * lo;
                        ga += wg[2*c+1] * hi;  pa += wp[2*c+1] * hi;
                    }
                    float ag = ga.x + ga.y;
                    float yt = __shfl_xor(ag, 32);      // lanes<32 get B.x_t
                    float yc = (i == 0 && k == 0) ? yt : y_prev;
                    y_prev = yt;
                    float gv = fast_tanh(ag - yc + b1g);
                    if (lane < 32) h1_sh[i & 3][k][lane] = gv;
                    pre_sh[i & 3][k][lane] = pa.x + pa.y + preb;
                }
            }
        }
        asm volatile("s_waitcnt vmcnt(0)" ::: "memory");   // drain dummies
    } else if (role == 1) {
        // ========== role1: tau + LTC recurrence (fused, lag 1) ==========
        h2 wr[16];
        const float* rw = (lane < 32) ? (fwrec + u * 32) : (swrec + u * 32);
        #pragma unroll
        for (int j = 0; j < 16; ++j)
            wr[j] = __builtin_amdgcn_cvt_pkrtz(rw[2*j], rw[2*j+1]);
        const float g2m = fg_w2[u] * (-L2E);
        const float b2m = fg_b2[0] * (-L2E);
        float h_st = 0.0f;

        for (int i = 0; i < NIT; ++i) {
            BAR();
            if (i >= 1 && i <= NG_) {
                const int gR = i - 1;
                const int sR = gR & 3;
                #pragma unroll
                for (int k = 0; k < GR_; ++k) {
                    // tau (consumed immediately, stays in regs)
                    float v  = rsum32(h1_sh[sR][k][u] * g2m);
                    float cs = frcp(1.0f + fexp2(v + b2m));
                    float rtf = frcp(10.0f - 9.99f * cs);
                    float rt  = (lane < 32) ? rtf : 0.2f;
                    // recurrence
                    const int sP = (k == 0) ? ((gR + 3) & 3) : sR;
                    const int kP = (k + GR_-1) & (GR_-1);
                    const uint4* hq = (const uint4*)(&hpk_sh[sP][kP][hb32 >> 1]);
                    float aA = 0.f, aB = 0.f;
                    #pragma unroll
                    for (int j = 0; j < 4; ++j) {
                        uint4 q = hq[j];
                        FDOT2(aA, bch2(q.x), wr[4*j+0]);
                        FDOT2(aB, bch2(q.y), wr[4*j+1]);
                        FDOT2(aA, bch2(q.z), wr[4*j+2]);
                        FDOT2(aB, bch2(q.w), wr[4*j+3]);
                    }
                    float upd = fast_tanh(aA + aB + pre_sh[sR][k][lane]);
                    h_st += (upd - h_st) * rt;
                    float hn = dppf<0xB1>(h_st);        // xor-1 neighbor
                    h2 pk = (lane & 1) ? __builtin_amdgcn_cvt_pkrtz(hn, h_st)
                                       : __builtin_amdgcn_cvt_pkrtz(h_st, hn);
                    hpk_sh[sR][k][lane >> 1] = bcu(pk);
                }
            }
        }
    } else if (role == 2) {
        // ========== role2: fusion only (lag 2) ==========
        h2 fw[32];
        #pragma unroll
        for (int j = 0; j < 32; ++j)
            fw[j] = __builtin_amdgcn_cvt_pkrtz(fu_w[lane*64 + 2*j], fu_w[lane*64 + 2*j+1]);
        const float fub = fu_b[lane];

        for (int i = 0; i < NIT; ++i) {
            BAR();
            if (i >= 2 && i <= NG_+1) {
                const int gF = i - 2;
                const int sF = gF & 3;
                const int sl = gF & 1;
                #pragma unroll
                for (int k = 0; k < GR_; ++k) {
                    const uint4* hq = (const uint4*)(&hpk_sh[sF][k][0]);
                    float aA = 0.f, aB = 0.f;
                    #pragma unroll
                    for (int j = 0; j < 8; ++j) {
                        uint4 q = hq[j];
                        FDOT2(aA, bch2(q.x), fw[4*j+0]);
                        FDOT2(aB, bch2(q.y), fw[4*j+1]);
                        FDOT2(aA, bch2(q.z), fw[4*j+2]);
                        FDOT2(aB, bch2(q.w), fw[4*j+3]);
                    }
                    float ltc = fast_tanh(aA + aB + fub);
                    float ln  = dppf<0xB1>(ltc);
                    h2 pk = (lane & 1) ? __builtin_amdgcn_cvt_pkrtz(ln, ltc)
                                       : __builtin_amdgcn_cvt_pkrtz(ltc, ln);
                    ltcpk[sl][k][lane >> 1] = bcu(pk);
                }
            }
        }
    } else {
        // ========== role3: attention + static-max softmax (lag 3) ==========
        h2 aw[16];
        #pragma unroll
        for (int j = 0; j < 16; ++j)
            aw[j] = __builtin_amdgcn_cvt_pkrtz(at_w1[u*64 + hb32 + 2*j],
                                               at_w1[u*64 + hb32 + 2*j+1]);
        const float ab1  = at_b1[u];
        const float aw2L = at_w2[u] * L2E;
        const float ab2L = at_b2[0] * L2E;
        float s_run = 0.0f, c_run = 0.0f;   // static max m=0 (|logit|<~2)

        for (int i = 0; i < NIT; ++i) {
            BAR();
            if (i >= 3) {                   // group i-3 (<= NG_-1 automatic)
                const int gA = i - 3;
                const int sl = gA & 1;
                #pragma unroll
                for (int k = 0; k < GR_; ++k) {
                    const uint4* lq = (const uint4*)(&ltcpk[sl][k][hb32 >> 1]);
                    float pA = 0.f, pB = 0.f;
                    #pragma unroll
                    for (int j = 0; j < 4; ++j) {
                        uint4 q = lq[j];
                        FDOT2(pA, bch2(q.x), aw[4*j+0]);
                        FDOT2(pB, bch2(q.y), aw[4*j+1]);
                        FDOT2(pA, bch2(q.z), aw[4*j+2]);
                        FDOT2(pB, bch2(q.w), aw[4*j+3]);
                    }
                    // own-lane ltc (packed layout: u16 index == lane)
                    const _Float16* lh = (const _Float16*)(&ltcpk[sl][k][0]);
                    float ltc = (float)lh[lane];
                    float p = pA + pB;
                    p += __shfl_xor(p, 32);
                    float a1 = fast_tanh(p + ab1);
                    float v  = rsum32(a1 * aw2L);
                    float pw = fexp2(v + ab2L);
                    s_run += pw;
                    c_run += pw * ltc;
                }
            }
        }
        ctx_sh[lane] = c_run * frcp(s_run);
    }

    __syncthreads();

    // =================== heads (by wid, off hot path) ===================
    if (wid == 0) {
        float r1 = d_b1[lane];
        #pragma unroll
        for (int c = 0; c < 16; ++c) {
            float4 cq = ((const float4*)ctx_sh)[c];
            float4 wq = ((const float4*)(d_w1 + lane*64))[c];
            r1 += wq.x*cq.x + wq.y*cq.y + wq.z*cq.z + wq.w*cq.w;
        }
        r1 = fmaxf(r1, 0.0f);
        #pragma unroll
        for (int kk = 0; kk < 5; ++kk) {
            float v = d_w2[kk*64 + lane] * r1;
            v += __shfl_xor(v, 1);  v += __shfl_xor(v, 2);
            v += __shfl_xor(v, 4);  v += __shfl_xor(v, 8);
            v += __shfl_xor(v, 16); v += __shfl_xor(v, 32);
            if (lane == 0) out[b*5 + kk] = v + d_b2[kk];
        }
    } else if (wid == 1) {
        float r1 = o_b1[lane];
        #pragma unroll
        for (int c = 0; c < 16; ++c) {
            float4 cq = ((const float4*)ctx_sh)[c];
            float4 wq = ((const float4*)(o_w1 + lane*64))[c];
            r1 += wq.x*cq.x + wq.y*cq.y + wq.z*cq.z + wq.w*cq.w;
        }
        r1 = fmaxf(r1, 0.0f);
        float acc = 0.0f;
        #pragma unroll
        for (int j = 0; j < 32; ++j) {
            float rj = __shfl(r1, hb32 + j);
            acc += o_w2[u*64 + hb32 + j] * rj;
        }
        acc += __shfl_xor(acc, 32);
        float r2 = fmaxf(acc + o_b2[u], 0.0f);
        float v  = o_w3[u] * r2;
        v += __shfl_xor(v, 1);  v += __shfl_xor(v, 2);
        v += __shfl_xor(v, 4);  v += __shfl_xor(v, 8);
        v += __shfl_xor(v, 16);
        if (lane == 0) {
            float e = fexp2((v + o_b3[0]) * -L2E);
            out[5*B + b] = frcp(1.0f + e);
        }
    } else if (wid == 2) {
        float acc = 0.0f;
        #pragma unroll
        for (int c = 0; c < 8; ++c) {
            float4 cq = ((const float4*)(ctx_sh + hb32))[c];
            float4 wq = ((const float4*)(i_w1 + u*64 + hb32))[c];
            acc += wq.x*cq.x + wq.y*cq.y + wq.z*cq.z + wq.w*cq.w;
        }
        acc += __shfl_xor(acc, 32);
        float r1 = fmaxf(acc + i_b1[u], 0.0f);
        float v  = i_w2[u] * r1;
        v += __shfl_xor(v, 1);  v += __shfl_xor(v, 2);
        v += __shfl_xor(v, 4);  v += __shfl_xor(v, 8);
        v += __shfl_xor(v, 16);
        if (lane == 0) {
            float e = fexp2((v + i_b2[0]) * -L2E);
            out[6*B + b] = frcp(1.0f + e);
        }
    }
}

extern "C" void kernel_launch(void* const* d_in, const int* in_sizes, int n_in,
                              void* d_out, int out_size, void* d_ws, size_t ws_size,
                              hipStream_t stream) {
    (void)n_in; (void)out_size; (void)d_ws; (void)ws_size;
    const float* X     = (const float*)d_in[0];
    const float* fg_w1 = (const float*)d_in[1];
    const float* fg_b1 = (const float*)d_in[2];
    const float* fg_w2 = (const float*)d_in[3];
    const float* fg_b2 = (const float*)d_in[4];
    const float* fwin  = (const float*)d_in[5];
    const float* fbin  = (const float*)d_in[6];
    const float* fwrec = (const float*)d_in[7];
    const float* swin  = (const float*)d_in[8];
    const float* sbin  = (const float*)d_in[9];
    const float* swrec = (const float*)d_in[10];
    const float* fu_w  = (const float*)d_in[11];
    const float* fu_b  = (const float*)d_in[12];
    const float* at_w1 = (const float*)d_in[13];
    const float* at_b1 = (const float*)d_in[14];
    const float* at_w2 = (const float*)d_in[15];
    const float* at_b2 = (const float*)d_in[16];
    const float* d_w1  = (const float*)d_in[17];
    const float* d_b1  = (const float*)d_in[18];
    const float* d_w2  = (const float*)d_in[19];
    const float* d_b2  = (const float*)d_in[20];
    const float* o_w1  = (const float*)d_in[21];
    const float* o_b1  = (const float*)d_in[22];
    const float* o_w2  = (const float*)d_in[23];
    const float* o_b2  = (const float*)d_in[24];
    const float* o_w3  = (const float*)d_in[25];
    const float* o_b3  = (const float*)d_in[26];
    const float* i_w1  = (const float*)d_in[27];
    const float* i_b1  = (const float*)d_in[28];
    const float* i_w2  = (const float*)d_in[29];
    const float* i_b2  = (const float*)d_in[30];
    float* out = (float*)d_out;

    const int B = in_sizes[0] / (T_ * D_);
    dim3 grid(B), block(256);
    hipLaunchKernelGGL(lnn_g8, grid, block, 0, stream,
        X, fg_w1, fg_b1, fg_w2, fg_b2, fwin, fbin, fwrec, swin, sbin, swrec,
        fu_w, fu_b, at_w1, at_b1, at_w2, at_b2, d_w1, d_b1, d_w2, d_b2,
        o_w1, o_b1, o_w2, o_b2, o_w3, o_b3, i_w1, i_b1, i_w2, i_b2, out, B);
}

// Round 10
// 138.557 us; speedup vs baseline: 5.2629x; 1.7637x over previous
//
#include <hip/hip_runtime.h>

// LNNRegression R10: MFMA-ized role0 (gate+pre+tau) and role2 (fusion).
// 4 waves, 8-step groups, dual-group (16 t) MFMA at odd iters, NIT=70.
//   role0: x DMA + [8x mfma 16x16x32_f16: gateAB|y|pre_f|pre_s] + y-shift +
//          tau (rsum16 DPP on C cols) -> rt_sh, pre -> pre_sh
//   role1: pure LTC recurrence (reads rt_sh broadcast), lag 2
//   role2: fusion via 2x b128 A-frag from hpk + 8 MFMA, lag 5/odd
//   role3: attention + static-max softmax (VALU), lag 6
// LDS rows padded (36/65) to avoid frag-read bank conflicts.

#define T_  512
#define D_  31
#define GR_ 8
#define NG_ 64
#define NIT 70
#define L2E 1.4426950408889634f

typedef decltype(__builtin_amdgcn_cvt_pkrtz(0.0f, 0.0f)) h2;  // <2 x half>
typedef _Float16 h8v __attribute__((ext_vector_type(8)));
typedef float    f4v __attribute__((ext_vector_type(4)));

__device__ __forceinline__ float fexp2(float x){ return __builtin_amdgcn_exp2f(x); }
__device__ __forceinline__ float frcp (float x){ return __builtin_amdgcn_rcpf(x); }
__device__ __forceinline__ float fast_tanh(float x){
    float e = fexp2(x * 2.8853900817779268f);
    return 1.0f - 2.0f * frcp(1.0f + e);
}
__device__ __forceinline__ h2 cvt2(float a, float b){ return __builtin_amdgcn_cvt_pkrtz(a, b); }
__device__ __forceinline__ h2 bch2(unsigned v){ return __builtin_bit_cast(h2, v); }
__device__ __forceinline__ unsigned bcu(h2 v){ return __builtin_bit_cast(unsigned, v); }

template <int CTRL>
__device__ __forceinline__ float dppf(float v){
    int r = __builtin_amdgcn_update_dpp(0, __builtin_bit_cast(int, v),
                                        CTRL, 0xf, 0xf, true);
    return __builtin_bit_cast(float, r);
}
__device__ __forceinline__ float rsum16(float v){   // sum within 16-lane rows
    v += dppf<0xB1>(v); v += dppf<0x4E>(v); v += dppf<0x141>(v); v += dppf<0x140>(v);
    return v;
}
__device__ __forceinline__ float rsum32(float v){   // sum within 32-lane halves
    v = rsum16(v);
    v += __builtin_bit_cast(float,
         __builtin_amdgcn_ds_swizzle(__builtin_bit_cast(int, v), 0x401F)); // xor16
    return v;
}

#if __has_builtin(__builtin_amdgcn_fdot2)
#define FDOT2(acc, a, b) (acc) = __builtin_amdgcn_fdot2((a), (b), (acc), false)
#else
#define FDOT2(acc, a, b) (acc) += (float)(a)[0]*(float)(b)[0] + (float)(a)[1]*(float)(b)[1]
#endif

#define MFMA16(A, Bf, Cf) __builtin_amdgcn_mfma_f32_16x16x32_f16((A), (Bf), (Cf), 0, 0, 0)

#define BAR() do { asm volatile("s_waitcnt lgkmcnt(0)" ::: "memory"); \
                   __builtin_amdgcn_s_barrier();                      \
                   asm volatile("" ::: "memory"); } while (0)

__launch_bounds__(256, 4)
__global__ void lnn_mf(
    const float* __restrict__ X,
    const float* __restrict__ fg_w1, const float* __restrict__ fg_b1,
    const float* __restrict__ fg_w2, const float* __restrict__ fg_b2,
    const float* __restrict__ fwin,  const float* __restrict__ fbin,
    const float* __restrict__ fwrec,
    const float* __restrict__ swin,  const float* __restrict__ sbin,
    const float* __restrict__ swrec,
    const float* __restrict__ fu_w,  const float* __restrict__ fu_b,
    const float* __restrict__ at_w1, const float* __restrict__ at_b1,
    const float* __restrict__ at_w2, const float* __restrict__ at_b2,
    const float* __restrict__ d_w1,  const float* __restrict__ d_b1,
    const float* __restrict__ d_w2,  const float* __restrict__ d_b2,
    const float* __restrict__ o_w1,  const float* __restrict__ o_b1,
    const float* __restrict__ o_w2,  const float* __restrict__ o_b2,
    const float* __restrict__ o_w3,  const float* __restrict__ o_b3,
    const float* __restrict__ i_w1,  const float* __restrict__ i_b1,
    const float* __restrict__ i_w2,  const float* __restrict__ i_b2,
    float* __restrict__ out, int B)
{
    const int b    = blockIdx.x;
    const int tx   = threadIdx.x;
    const int wid  = tx >> 6;
    const int lane = tx & 63;
    const int u    = lane & 31;
    const int hb32 = lane & 32;
    const int role = (wid + b) & 3;

    __shared__ __align__(16) float    xr_sh [4][GR_][36];  // x ring (31+pad)
    __shared__ float    xdm   [36];                        // dummy DMA dest
    __shared__ float    pre_sh[4][GR_][65];                // pre_f|pre_s (bias incl.)
    __shared__ float    rt_sh [4][GR_];                    // 1/tau_fast
    __shared__ __align__(16) unsigned hpk_sh[4][GR_][36];  // h packed f16x2
    __shared__ __align__(16) unsigned ltcpk [4][GR_][36];  // ltc packed f16x2
    __shared__ float    ctx_sh[64];

    if (tx < 32) hpk_sh[3][GR_-1][tx] = 0u;             // h_{-1} = 0
    if (tx < 32) xr_sh[tx >> 3][tx & 7][31] = 0.0f;     // k=31 pad = 0

    if (role == 0) {
        // ===== role0: x DMA + MFMA gate/y/pre + y-shift + tau =====
        const int col = lane & 15, kb = lane >> 4;
        h8v wB[8];
        #pragma unroll
        for (int c = 0; c < 8; ++c) {
            float wv[8];
            #pragma unroll
            for (int j = 0; j < 8; ++j) {
                const int k = kb*8 + j;
                float v = 0.0f;
                if (k < 31) {
                    const int uu = 16*(c & 1) + col;
                    if (c < 2)      v = fg_w1[uu*62 + k] + fg_w1[uu*62 + 31 + k];
                    else if (c < 4) v = fg_w1[uu*62 + 31 + k];
                    else if (c < 6) v = fwin[uu*31 + k];
                    else            v = swin[uu*31 + k];
                }
                wv[j] = v;
            }
            uint4 qq = { bcu(cvt2(wv[0],wv[1])), bcu(cvt2(wv[2],wv[3])),
                         bcu(cvt2(wv[4],wv[5])), bcu(cvt2(wv[6],wv[7])) };
            wB[c] = __builtin_bit_cast(h8v, qq);
        }
        const float b1c[2] = { fg_b1[col], fg_b1[16 + col] };
        const float pb[4]  = { fbin[col], fbin[16+col], sbin[col], sbin[16+col] };
        const float w2n[2] = { fg_w2[col] * (-L2E), fg_w2[16+col] * (-L2E) };
        const float b2n    = fg_b2[0] * (-L2E);
        const unsigned* Xu = (const unsigned*)(X + (size_t)b * T_ * D_ + lane);
        float ypv[2] = {0.0f, 0.0f};
        asm volatile("s_waitcnt vmcnt(0)" ::: "memory");

        // prologue: DMA groups 0,1
        #pragma unroll
        for (int gg = 0; gg < 2; ++gg)
            #pragma unroll
            for (int k = 0; k < GR_; ++k)
                if (lane < 31)
                    __builtin_amdgcn_global_load_lds(
                        (const __attribute__((address_space(1))) unsigned*)(Xu + (size_t)(GR_*gg + k) * 31),
                        (__attribute__((address_space(3))) unsigned*)(&xr_sh[gg][k][0]),
                        4, 0, 0);

        for (int i = 0; i < NIT; ++i) {
            asm volatile("s_waitcnt vmcnt(8)" ::: "memory");
            BAR();
            {   // DMA group i+2 (dummy tail keeps vmcnt uniform)
                const int gq = i + 2;
                #pragma unroll
                for (int k = 0; k < GR_; ++k) {
                    int tl = GR_*gq + k; if (tl > 511) tl = 511;
                    float* dst = (gq <= NG_-1) ? &xr_sh[gq & 3][k][0] : &xdm[0];
                    if (lane < 31)
                        __builtin_amdgcn_global_load_lds(
                            (const __attribute__((address_space(1))) unsigned*)(Xu + (size_t)tl * 31),
                            (__attribute__((address_space(3))) unsigned*)dst,
                            4, 0, 0);
                }
            }
            if ((i & 1) && i <= NG_-1) {        // dual-group (i-1, i)
                const int sA_ = (i-1) & 3, sB_ = i & 3;
                const float* xrow = (col < 8) ? &xr_sh[sA_][col][kb*8]
                                              : &xr_sh[sB_][col-8][kb*8];
                float4 xa = *(const float4*)xrow;
                float4 xb = *(const float4*)(xrow + 4);
                uint4 aq = { bcu(cvt2(xa.x,xa.y)), bcu(cvt2(xa.z,xa.w)),
                             bcu(cvt2(xb.x,xb.y)), bcu(cvt2(xb.z,xb.w)) };
                h8v Af = __builtin_bit_cast(h8v, aq);
                f4v C[8];
                #pragma unroll
                for (int c = 0; c < 8; ++c) {
                    f4v z = {0.f, 0.f, 0.f, 0.f};
                    C[c] = MFMA16(Af, wB[c], z);
                }
                const int tslot = (kb < 2) ? sA_ : sB_;
                const int tb    = (kb & 1) * 4;
                float tp[4] = {0.f, 0.f, 0.f, 0.f};
                #pragma unroll
                for (int p = 0; p < 2; ++p) {
                    f4v G = C[p], Y = C[2+p];
                    if (i == 1) ypv[p] = __shfl(Y[0], col);     // dx_0 = 0
                    float ylast = __shfl(Y[3], 48 + col);       // row15 -> next yp
                    float yup   = __shfl(Y[3], (lane - 16) & 63);
                    float ysh0  = (kb == 0) ? ypv[p] : yup;
                    float h1v[4];
                    h1v[0] = fast_tanh(G[0] - ysh0 + b1c[p]);
                    h1v[1] = fast_tanh(G[1] - Y[0] + b1c[p]);
                    h1v[2] = fast_tanh(G[2] - Y[1] + b1c[p]);
                    h1v[3] = fast_tanh(G[3] - Y[2] + b1c[p]);
                    ypv[p] = ylast;
                    #pragma unroll
                    for (int r = 0; r < 4; ++r) tp[r] += h1v[r] * w2n[p];
                }
                #pragma unroll
                for (int r = 0; r < 4; ++r) {   // tau per row
                    float s  = rsum16(tp[r]) + b2n;
                    float cs = frcp(1.0f + fexp2(s));
                    float rt = frcp(10.0f - 9.99f * cs);
                    if (col == 0) rt_sh[tslot][tb + r] = rt;
                }
                #pragma unroll
                for (int c = 4; c < 8; ++c) {   // pre outputs
                    const int uo = (c < 6 ? 0 : 32) + 16*(c & 1) + col;
                    #pragma unroll
                    for (int r = 0; r < 4; ++r)
                        pre_sh[tslot][tb + r][uo] = C[c][r] + pb[c-4];
                }
            }
        }
        asm volatile("s_waitcnt vmcnt(0)" ::: "memory");
    } else if (role == 1) {
        // ===== role1: pure LTC recurrence (lag 2) =====
        h2 wr[16];
        const float* rw = (lane < 32) ? (fwrec + u * 32) : (swrec + u * 32);
        #pragma unroll
        for (int j = 0; j < 16; ++j) wr[j] = cvt2(rw[2*j], rw[2*j+1]);
        float h_st = 0.0f;

        for (int i = 0; i < NIT; ++i) {
            BAR();
            if (i >= 2 && i <= NG_+1) {
                const int gR = i - 2;
                const int sR = gR & 3;
                #pragma unroll
                for (int k = 0; k < GR_; ++k) {
                    float rt = (lane < 32) ? rt_sh[sR][k] : 0.2f;
                    const int sP = (k == 0) ? ((gR + 3) & 3) : sR;
                    const int kP = (k + GR_-1) & (GR_-1);
                    const uint4* hq = (const uint4*)(&hpk_sh[sP][kP][hb32 >> 1]);
                    float aA = 0.f, aB = 0.f;
                    #pragma unroll
                    for (int j = 0; j < 4; ++j) {
                        uint4 q = hq[j];
                        FDOT2(aA, bch2(q.x), wr[4*j+0]);
                        FDOT2(aB, bch2(q.y), wr[4*j+1]);
                        FDOT2(aA, bch2(q.z), wr[4*j+2]);
                        FDOT2(aB, bch2(q.w), wr[4*j+3]);
                    }
                    float upd = fast_tanh(aA + aB + pre_sh[sR][k][lane]);
                    h_st += (upd - h_st) * rt;
                    float hn = dppf<0xB1>(h_st);
                    h2 pk = (lane & 1) ? cvt2(hn, h_st) : cvt2(h_st, hn);
                    hpk_sh[sR][k][lane >> 1] = bcu(pk);
                }
            }
        }
    } else if (role == 2) {
        // ===== role2: fusion via MFMA (dual-group, lag 5, odd iters) =====
        const int col = lane & 15, kb = lane >> 4;
        h8v wF[8];                      // [kc*4 + nc]
        #pragma unroll
        for (int kc = 0; kc < 2; ++kc)
            #pragma unroll
            for (int nc = 0; nc < 4; ++nc) {
                float wv[8];
                #pragma unroll
                for (int j = 0; j < 8; ++j)
                    wv[j] = fu_w[(16*nc + col)*64 + 32*kc + 8*kb + j];
                uint4 qq = { bcu(cvt2(wv[0],wv[1])), bcu(cvt2(wv[2],wv[3])),
                             bcu(cvt2(wv[4],wv[5])), bcu(cvt2(wv[6],wv[7])) };
                wF[kc*4 + nc] = __builtin_bit_cast(h8v, qq);
            }
        const float fb4[4] = { fu_b[col], fu_b[16+col], fu_b[32+col], fu_b[48+col] };

        for (int i = 0; i < NIT; ++i) {
            BAR();
            if ((i & 1) && i >= 5 && i <= 67) {     // dual-group (i-5, i-4)
                const int s0 = (i-5) & 3, s1 = (i-4) & 3;
                const unsigned* hrow = (col < 8) ? &hpk_sh[s0][col][0]
                                                 : &hpk_sh[s1][col-8][0];
                uint4 a0q = *(const uint4*)(hrow + kb*4);
                uint4 a1q = *(const uint4*)(hrow + kb*4 + 16);
                h8v A0 = __builtin_bit_cast(h8v, a0q);
                h8v A1 = __builtin_bit_cast(h8v, a1q);
                const int tslot = (kb < 2) ? s0 : s1;
                const int tb    = (kb & 1) * 4;
                #pragma unroll
                for (int nc = 0; nc < 4; ++nc) {
                    f4v c4 = {0.f, 0.f, 0.f, 0.f};
                    c4 = MFMA16(A0, wF[nc],     c4);
                    c4 = MFMA16(A1, wF[4 + nc], c4);
                    #pragma unroll
                    for (int r = 0; r < 4; ++r) {
                        float v  = fast_tanh(c4[r] + fb4[nc]);
                        float vn = dppf<0xB1>(v);
                        h2 pk = (col & 1) ? cvt2(vn, v) : cvt2(v, vn);
                        if (!(col & 1))
                            ltcpk[tslot][tb + r][(16*nc + col) >> 1] = bcu(pk);
                    }
                }
            }
        }
    } else {
        // ===== role3: attention + static-max softmax (lag 6) =====
        h2 aw[16];
        const int col = lane & 15; (void)col;
        #pragma unroll
        for (int j = 0; j < 16; ++j)
            aw[j] = cvt2(at_w1[u*64 + hb32 + 2*j], at_w1[u*64 + hb32 + 2*j+1]);
        const float ab1  = at_b1[u];
        const float aw2L = at_w2[u] * L2E;
        const float ab2L = at_b2[0] * L2E;
        float s_run = 0.0f, c_run = 0.0f;

        for (int i = 0; i < NIT; ++i) {
            BAR();
            if (i >= 6) {                       // group i-6 (<= NG_-1 automatic)
                const int sl = (i - 6) & 3;
                #pragma unroll
                for (int k = 0; k < GR_; ++k) {
                    const uint4* lq = (const uint4*)(&ltcpk[sl][k][hb32 >> 1]);
                    float pA = 0.f, pB = 0.f;
                    #pragma unroll
                    for (int j = 0; j < 4; ++j) {
                        uint4 q = lq[j];
                        FDOT2(pA, bch2(q.x), aw[4*j+0]);
                        FDOT2(pB, bch2(q.y), aw[4*j+1]);
                        FDOT2(pA, bch2(q.z), aw[4*j+2]);
                        FDOT2(pB, bch2(q.w), aw[4*j+3]);
                    }
                    float ltc = (float)((const _Float16*)(&ltcpk[sl][k][0]))[lane];
                    float p = pA + pB;
                    p += __shfl_xor(p, 32);
                    float a1 = fast_tanh(p + ab1);
                    float v  = rsum32(a1 * aw2L);
                    float pw = fexp2(v + ab2L);
                    s_run += pw;
                    c_run += pw * ltc;
                }
            }
        }
        ctx_sh[lane] = c_run * frcp(s_run);
    }

    __syncthreads();

    // =================== heads (by wid) ===================
    if (wid == 0) {
        float r1 = d_b1[lane];
        #pragma unroll
        for (int c = 0; c < 16; ++c) {
            float4 cq = ((const float4*)ctx_sh)[c];
            float4 wq = ((const float4*)(d_w1 + lane*64))[c];
            r1 += wq.x*cq.x + wq.y*cq.y + wq.z*cq.z + wq.w*cq.w;
        }
        r1 = fmaxf(r1, 0.0f);
        #pragma unroll
        for (int kk = 0; kk < 5; ++kk) {
            float v = d_w2[kk*64 + lane] * r1;
            v += __shfl_xor(v, 1);  v += __shfl_xor(v, 2);
            v += __shfl_xor(v, 4);  v += __shfl_xor(v, 8);
            v += __shfl_xor(v, 16); v += __shfl_xor(v, 32);
            if (lane == 0) out[b*5 + kk] = v + d_b2[kk];
        }
    } else if (wid == 1) {
        float r1 = o_b1[lane];
        #pragma unroll
        for (int c = 0; c < 16; ++c) {
            float4 cq = ((const float4*)ctx_sh)[c];
            float4 wq = ((const float4*)(o_w1 + lane*64))[c];
            r1 += wq.x*cq.x + wq.y*cq.y + wq.z*cq.z + wq.w*cq.w;
        }
        r1 = fmaxf(r1, 0.0f);
        float acc = 0.0f;
        #pragma unroll
        for (int j = 0; j < 32; ++j) {
            float rj = __shfl(r1, hb32 + j);
            acc += o_w2[u*64 + hb32 + j] * rj;
        }
        acc += __shfl_xor(acc, 32);
        float r2 = fmaxf(acc + o_b2[u], 0.0f);
        float v  = o_w3[u] * r2;
        v += __shfl_xor(v, 1);  v += __shfl_xor(v, 2);
        v += __shfl_xor(v, 4);  v += __shfl_xor(v, 8);
        v += __shfl_xor(v, 16);
        if (lane == 0) {
            float e = fexp2((v + o_b3[0]) * -L2E);
            out[5*B + b] = frcp(1.0f + e);
        }
    } else if (wid == 2) {
        float acc = 0.0f;
        #pragma unroll
        for (int c = 0; c < 8; ++c) {
            float4 cq = ((const float4*)(ctx_sh + hb32))[c];
            float4 wq = ((const float4*)(i_w1 + u*64 + hb32))[c];
            acc += wq.x*cq.x + wq.y*cq.y + wq.z*cq.z + wq.w*cq.w;
        }
        acc += __shfl_xor(acc, 32);
        float r1 = fmaxf(acc + i_b1[u], 0.0f);
        float v  = i_w2[u] * r1;
        v += __shfl_xor(v, 1);  v += __shfl_xor(v, 2);
        v += __shfl_xor(v, 4);  v += __shfl_xor(v, 8);
        v += __shfl_xor(v, 16);
        if (lane == 0) {
            float e = fexp2((v + i_b2[0]) * -L2E);
            out[6*B + b] = frcp(1.0f + e);
        }
    }
}

extern "C" void kernel_launch(void* const* d_in, const int* in_sizes, int n_in,
                              void* d_out, int out_size, void* d_ws, size_t ws_size,
                              hipStream_t stream) {
    (void)n_in; (void)out_size; (void)d_ws; (void)ws_size;
    const float* X     = (const float*)d_in[0];
    const float* fg_w1 = (const float*)d_in[1];
    const float* fg_b1 = (const float*)d_in[2];
    const float* fg_w2 = (const float*)d_in[3];
    const float* fg_b2 = (const float*)d_in[4];
    const float* fwin  = (const float*)d_in[5];
    const float* fbin  = (const float*)d_in[6];
    const float* fwrec = (const float*)d_in[7];
    const float* swin  = (const float*)d_in[8];
    const float* sbin  = (const float*)d_in[9];
    const float* swrec = (const float*)d_in[10];
    const float* fu_w  = (const float*)d_in[11];
    const float* fu_b  = (const float*)d_in[12];
    const float* at_w1 = (const float*)d_in[13];
    const float* at_b1 = (const float*)d_in[14];
    const float* at_w2 = (const float*)d_in[15];
    const float* at_b2 = (const float*)d_in[16];
    const float* d_w1  = (const float*)d_in[17];
    const float* d_b1  = (const float*)d_in[18];
    const float* d_w2  = (const float*)d_in[19];
    const float* d_b2  = (const float*)d_in[20];
    const float* o_w1  = (const float*)d_in[21];
    const float* o_b1  = (const float*)d_in[22];
    const float* o_w2  = (const float*)d_in[23];
    const float* o_b2  = (const float*)d_in[24];
    const float* o_w3  = (const float*)d_in[25];
    const float* o_b3  = (const float*)d_in[26];
    const float* i_w1  = (const float*)d_in[27];
    const float* i_b1  = (const float*)d_in[28];
    const float* i_w2  = (const float*)d_in[29];
    const float* i_b2  = (const float*)d_in[30];
    float* out = (float*)d_out;

    const int B = in_sizes[0] / (T_ * D_);
    dim3 grid(B), block(256);
    hipLaunchKernelGGL(lnn_mf, grid, block, 0, stream,
        X, fg_w1, fg_b1, fg_w2, fg_b2, fwin, fbin, fwrec, swin, sbin, swrec,
        fu_w, fu_b, at_w1, at_b1, at_w2, at_b2, d_w1, d_b1, d_w2, d_b2,
        o_w1, o_b1, o_w2, o_b2, o_w3, o_b3, i_w1, i_b1, i_w2, i_b2, out, B);
}

// Round 11
// 129.913 us; speedup vs baseline: 5.6130x; 1.0665x over previous
//
#include <hip/hip_runtime.h>

// LNNRegression R11: MFMA gate (R10) + MFMA fusion+attention MERGED in one
// wave + recurrence SPLIT by cell across two waves (2 lanes/unit, K=16).
// 4 waves, 8-step groups, dual-group (16 t) MFMA at odd iters, NIT=68.
//   role0: x DMA + MFMA gate/y/pre + tau -> rt_sh, pre_sh
//   role1: FAST LTC recurrence (lag 2), split-K pairs, writes hpk j0..15
//   role2: SLOW LTC recurrence (lag 2), writes hpk j16..31
//   role3: fusion MFMA -> ltcpk -> attention MFMA -> pw -> softmax accum
//          (dual-group i-5,i-4 at odd i)

#define T_  512
#define D_  31
#define GR_ 8
#define NG_ 64
#define NIT 68
#define L2E 1.4426950408889634f

typedef decltype(__builtin_amdgcn_cvt_pkrtz(0.0f, 0.0f)) h2;  // <2 x half>
typedef _Float16 h8v __attribute__((ext_vector_type(8)));
typedef float    f4v __attribute__((ext_vector_type(4)));

__device__ __forceinline__ float fexp2(float x){ return __builtin_amdgcn_exp2f(x); }
__device__ __forceinline__ float frcp (float x){ return __builtin_amdgcn_rcpf(x); }
__device__ __forceinline__ float fast_tanh(float x){
    float e = fexp2(x * 2.8853900817779268f);
    return 1.0f - 2.0f * frcp(1.0f + e);
}
__device__ __forceinline__ h2 cvt2(float a, float b){ return __builtin_amdgcn_cvt_pkrtz(a, b); }
__device__ __forceinline__ h2 bch2(unsigned v){ return __builtin_bit_cast(h2, v); }
__device__ __forceinline__ unsigned bcu(h2 v){ return __builtin_bit_cast(unsigned, v); }

template <int CTRL>
__device__ __forceinline__ float dppf(float v){
    int r = __builtin_amdgcn_update_dpp(0, __builtin_bit_cast(int, v),
                                        CTRL, 0xf, 0xf, true);
    return __builtin_bit_cast(float, r);
}
__device__ __forceinline__ float rsum16(float v){
    v += dppf<0xB1>(v); v += dppf<0x4E>(v); v += dppf<0x141>(v); v += dppf<0x140>(v);
    return v;
}

#if __has_builtin(__builtin_amdgcn_fdot2)
#define FDOT2(acc, a, b) (acc) = __builtin_amdgcn_fdot2((a), (b), (acc), false)
#else
#define FDOT2(acc, a, b) (acc) += (float)(a)[0]*(float)(b)[0] + (float)(a)[1]*(float)(b)[1]
#endif

#define MFMA16(A, Bf, Cf) __builtin_amdgcn_mfma_f32_16x16x32_f16((A), (Bf), (Cf), 0, 0, 0)

#define BAR() do { asm volatile("s_waitcnt lgkmcnt(0)" ::: "memory"); \
                   __builtin_amdgcn_s_barrier();                      \
                   asm volatile("" ::: "memory"); } while (0)

__launch_bounds__(256, 4)
__global__ void lnn_mf(
    const float* __restrict__ X,
    const float* __restrict__ fg_w1, const float* __restrict__ fg_b1,
    const float* __restrict__ fg_w2, const float* __restrict__ fg_b2,
    const float* __restrict__ fwin,  const float* __restrict__ fbin,
    const float* __restrict__ fwrec,
    const float* __restrict__ swin,  const float* __restrict__ sbin,
    const float* __restrict__ swrec,
    const float* __restrict__ fu_w,  const float* __restrict__ fu_b,
    const float* __restrict__ at_w1, const float* __restrict__ at_b1,
    const float* __restrict__ at_w2, const float* __restrict__ at_b2,
    const float* __restrict__ d_w1,  const float* __restrict__ d_b1,
    const float* __restrict__ d_w2,  const float* __restrict__ d_b2,
    const float* __restrict__ o_w1,  const float* __restrict__ o_b1,
    const float* __restrict__ o_w2,  const float* __restrict__ o_b2,
    const float* __restrict__ o_w3,  const float* __restrict__ o_b3,
    const float* __restrict__ i_w1,  const float* __restrict__ i_b1,
    const float* __restrict__ i_w2,  const float* __restrict__ i_b2,
    float* __restrict__ out, int B)
{
    const int b    = blockIdx.x;
    const int tx   = threadIdx.x;
    const int wid  = tx >> 6;
    const int lane = tx & 63;
    const int u    = lane & 31;
    const int hb32 = lane & 32;
    const int role = (wid + b) & 3;

    __shared__ __align__(16) float    xr_sh [4][GR_][36];  // x ring (31+pad)
    __shared__ float    xdm   [36];                        // dummy DMA dest
    __shared__ float    pre_sh[4][GR_][65];                // pre_f|pre_s
    __shared__ float    rt_sh [4][GR_];                    // 1/tau_fast
    __shared__ __align__(16) unsigned hpk_sh[4][GR_][36];  // h packed f16x2
    __shared__ __align__(16) unsigned ltcpk [4][GR_][36];  // ltc packed f16x2
    __shared__ float    pw_sh [16];                        // softmax weights
    __shared__ float    ctx_sh[64];

    if (tx < 32) hpk_sh[3][GR_-1][tx] = 0u;             // h_{-1} = 0
    if (tx < 32) xr_sh[tx >> 3][tx & 7][31] = 0.0f;     // k=31 pad = 0

    if (role == 0) {
        // ===== role0: x DMA + MFMA gate/y/pre + y-shift + tau =====
        const int col = lane & 15, kb = lane >> 4;
        h8v wB[8];
        #pragma unroll
        for (int c = 0; c < 8; ++c) {
            float wv[8];
            #pragma unroll
            for (int j = 0; j < 8; ++j) {
                const int k = kb*8 + j;
                float v = 0.0f;
                if (k < 31) {
                    const int uu = 16*(c & 1) + col;
                    if (c < 2)      v = fg_w1[uu*62 + k] + fg_w1[uu*62 + 31 + k];
                    else if (c < 4) v = fg_w1[uu*62 + 31 + k];
                    else if (c < 6) v = fwin[uu*31 + k];
                    else            v = swin[uu*31 + k];
                }
                wv[j] = v;
            }
            uint4 qq = { bcu(cvt2(wv[0],wv[1])), bcu(cvt2(wv[2],wv[3])),
                         bcu(cvt2(wv[4],wv[5])), bcu(cvt2(wv[6],wv[7])) };
            wB[c] = __builtin_bit_cast(h8v, qq);
        }
        const float b1c[2] = { fg_b1[col], fg_b1[16 + col] };
        const float pb[4]  = { fbin[col], fbin[16+col], sbin[col], sbin[16+col] };
        const float w2n[2] = { fg_w2[col] * (-L2E), fg_w2[16+col] * (-L2E) };
        const float b2n    = fg_b2[0] * (-L2E);
        const unsigned* Xu = (const unsigned*)(X + (size_t)b * T_ * D_ + lane);
        float ypv[2] = {0.0f, 0.0f};
        asm volatile("s_waitcnt vmcnt(0)" ::: "memory");

        // prologue: DMA groups 0,1
        #pragma unroll
        for (int gg = 0; gg < 2; ++gg)
            #pragma unroll
            for (int k = 0; k < GR_; ++k)
                if (lane < 31)
                    __builtin_amdgcn_global_load_lds(
                        (const __attribute__((address_space(1))) unsigned*)(Xu + (size_t)(GR_*gg + k) * 31),
                        (__attribute__((address_space(3))) unsigned*)(&xr_sh[gg][k][0]),
                        4, 0, 0);

        for (int i = 0; i < NIT; ++i) {
            asm volatile("s_waitcnt vmcnt(8)" ::: "memory");
            BAR();
            {   // DMA group i+2 (dummy tail keeps vmcnt uniform)
                const int gq = i + 2;
                #pragma unroll
                for (int k = 0; k < GR_; ++k) {
                    int tl = GR_*gq + k; if (tl > 511) tl = 511;
                    float* dst = (gq <= NG_-1) ? &xr_sh[gq & 3][k][0] : &xdm[0];
                    if (lane < 31)
                        __builtin_amdgcn_global_load_lds(
                            (const __attribute__((address_space(1))) unsigned*)(Xu + (size_t)tl * 31),
                            (__attribute__((address_space(3))) unsigned*)dst,
                            4, 0, 0);
                }
            }
            if ((i & 1) && i <= NG_-1) {        // dual-group (i-1, i)
                const int sA_ = (i-1) & 3, sB_ = i & 3;
                const float* xrow = (col < 8) ? &xr_sh[sA_][col][kb*8]
                                              : &xr_sh[sB_][col-8][kb*8];
                float4 xa = *(const float4*)xrow;
                float4 xb = *(const float4*)(xrow + 4);
                uint4 aq = { bcu(cvt2(xa.x,xa.y)), bcu(cvt2(xa.z,xa.w)),
                             bcu(cvt2(xb.x,xb.y)), bcu(cvt2(xb.z,xb.w)) };
                h8v Af = __builtin_bit_cast(h8v, aq);
                f4v C[8];
                #pragma unroll
                for (int c = 0; c < 8; ++c) {
                    f4v z = {0.f, 0.f, 0.f, 0.f};
                    C[c] = MFMA16(Af, wB[c], z);
                }
                const int tslot = (kb < 2) ? sA_ : sB_;
                const int tb    = (kb & 1) * 4;
                float tp[4] = {0.f, 0.f, 0.f, 0.f};
                #pragma unroll
                for (int p = 0; p < 2; ++p) {
                    f4v G = C[p], Y = C[2+p];
                    if (i == 1) ypv[p] = __shfl(Y[0], col);     // dx_0 = 0
                    float ylast = __shfl(Y[3], 48 + col);       // row15 -> next
                    float yup   = __shfl(Y[3], (lane - 16) & 63);
                    float ysh0  = (kb == 0) ? ypv[p] : yup;
                    float h1v[4];
                    h1v[0] = fast_tanh(G[0] - ysh0 + b1c[p]);
                    h1v[1] = fast_tanh(G[1] - Y[0] + b1c[p]);
                    h1v[2] = fast_tanh(G[2] - Y[1] + b1c[p]);
                    h1v[3] = fast_tanh(G[3] - Y[2] + b1c[p]);
                    ypv[p] = ylast;
                    #pragma unroll
                    for (int r = 0; r < 4; ++r) tp[r] += h1v[r] * w2n[p];
                }
                #pragma unroll
                for (int r = 0; r < 4; ++r) {   // tau per row
                    float s  = rsum16(tp[r]) + b2n;
                    float cs = frcp(1.0f + fexp2(s));
                    float rt = frcp(10.0f - 9.99f * cs);
                    if (col == 0) rt_sh[tslot][tb + r] = rt;
                }
                #pragma unroll
                for (int c = 4; c < 8; ++c) {   // pre outputs
                    const int uo = (c < 6 ? 0 : 32) + 16*(c & 1) + col;
                    #pragma unroll
                    for (int r = 0; r < 4; ++r)
                        pre_sh[tslot][tb + r][uo] = C[c][r] + pb[c-4];
                }
            }
        }
        asm volatile("s_waitcnt vmcnt(0)" ::: "memory");
    } else if (role == 1 || role == 2) {
        // ===== role1/2: LTC recurrence, one cell per wave, K split in pairs ====
        const bool slow = (role == 2);
        const int  uu   = lane >> 1;        // unit 0..31 (within cell)
        const int  kh   = lane & 1;         // K half
        const int  jb   = slow ? 16 : 0;    // hpk j base
        const int  ub   = slow ? 32 : 0;    // pre column base
        h2 wr[8];
        const float* rw = (slow ? swrec : fwrec) + uu*32 + kh*16;
        #pragma unroll
        for (int j = 0; j < 8; ++j) wr[j] = cvt2(rw[2*j], rw[2*j+1]);
        float h_st = 0.0f;

        for (int i = 0; i < NIT; ++i) {
            BAR();
            if (i >= 2 && i <= NG_+1) {
                const int gR = i - 2;
                const int sR = gR & 3;
                #pragma unroll
                for (int k = 0; k < GR_; ++k) {
                    const int sP = (k == 0) ? ((gR + 3) & 3) : sR;
                    const int kP = (k + GR_-1) & (GR_-1);
                    const uint4* hq = (const uint4*)(&hpk_sh[sP][kP][jb + kh*8]);
                    uint4 q0 = hq[0], q1 = hq[1];
                    float aA = 0.f, aB = 0.f;
                    FDOT2(aA, bch2(q0.x), wr[0]); FDOT2(aB, bch2(q0.y), wr[1]);
                    FDOT2(aA, bch2(q0.z), wr[2]); FDOT2(aB, bch2(q0.w), wr[3]);
                    FDOT2(aA, bch2(q1.x), wr[4]); FDOT2(aB, bch2(q1.y), wr[5]);
                    FDOT2(aA, bch2(q1.z), wr[6]); FDOT2(aB, bch2(q1.w), wr[7]);
                    float v = aA + aB;
                    v += dppf<0xB1>(v);             // combine K halves (pairs)
                    float upd = fast_tanh(v + pre_sh[sR][k][ub + uu]);
                    float rt  = slow ? 0.2f : rt_sh[sR][k];
                    h_st += (upd - h_st) * rt;
                    float ho = dppf<0x4E>(h_st);    // lane 4j <- lane 4j+2
                    if ((lane & 3) == 0)
                        hpk_sh[sR][k][jb + (lane >> 2)] = bcu(cvt2(h_st, ho));
                }
            }
        }
    } else {
        // ===== role3: fusion MFMA -> attention MFMA -> softmax =====
        const int col = lane & 15, kb = lane >> 4;
        h8v wF[8];                      // fusion B-frags [kc*4 + nc]
        #pragma unroll
        for (int kc = 0; kc < 2; ++kc)
            #pragma unroll
            for (int nc = 0; nc < 4; ++nc) {
                float wv[8];
                #pragma unroll
                for (int j = 0; j < 8; ++j)
                    wv[j] = fu_w[(16*nc + col)*64 + 32*kc + 8*kb + j];
                uint4 qq = { bcu(cvt2(wv[0],wv[1])), bcu(cvt2(wv[2],wv[3])),
                             bcu(cvt2(wv[4],wv[5])), bcu(cvt2(wv[6],wv[7])) };
                wF[kc*4 + nc] = __builtin_bit_cast(h8v, qq);
            }
        const float fb4[4] = { fu_b[col], fu_b[16+col], fu_b[32+col], fu_b[48+col] };
        h8v wA[4];                      // attention B-frags [kt*2 + nt]
        #pragma unroll
        for (int kt = 0; kt < 2; ++kt)
            #pragma unroll
            for (int nt = 0; nt < 2; ++nt) {
                float wv[8];
                #pragma unroll
                for (int j = 0; j < 8; ++j)
                    wv[j] = at_w1[(nt*16 + col)*64 + kt*32 + 8*kb + j];
                uint4 qq = { bcu(cvt2(wv[0],wv[1])), bcu(cvt2(wv[2],wv[3])),
                             bcu(cvt2(wv[4],wv[5])), bcu(cvt2(wv[6],wv[7])) };
                wA[kt*2 + nt] = __builtin_bit_cast(h8v, qq);
            }
        const float ab1v[2] = { at_b1[col], at_b1[16 + col] };
        const float w2L[2]  = { at_w2[col] * L2E, at_w2[16 + col] * L2E };
        const float ab2L    = at_b2[0] * L2E;
        float s_run = 0.0f, c_run = 0.0f;

        for (int i = 0; i < NIT; ++i) {
            BAR();
            if ((i & 1) && i >= 5 && i <= 67) {     // dual-group (i-5, i-4)
                const int s0 = (i-5) & 3, s1 = (i-4) & 3;
                // ---- fusion ----
                const unsigned* hrow = (col < 8) ? &hpk_sh[s0][col][0]
                                                 : &hpk_sh[s1][col-8][0];
                uint4 a0q = *(const uint4*)(hrow + kb*4);
                uint4 a1q = *(const uint4*)(hrow + kb*4 + 16);
                h8v A0 = __builtin_bit_cast(h8v, a0q);
                h8v A1 = __builtin_bit_cast(h8v, a1q);
                const int tslot = (kb < 2) ? s0 : s1;
                const int tb    = (kb & 1) * 4;
                #pragma unroll
                for (int nc = 0; nc < 4; ++nc) {
                    f4v c4 = {0.f, 0.f, 0.f, 0.f};
                    c4 = MFMA16(A0, wF[nc],     c4);
                    c4 = MFMA16(A1, wF[4 + nc], c4);
                    #pragma unroll
                    for (int r = 0; r < 4; ++r) {
                        float v  = fast_tanh(c4[r] + fb4[nc]);
                        float vn = dppf<0xB1>(v);
                        h2 pk = (col & 1) ? cvt2(vn, v) : cvt2(v, vn);
                        if (!(col & 1))
                            ltcpk[tslot][tb + r][(16*nc + col) >> 1] = bcu(pk);
                    }
                }
                // ---- attention (same wave; lgkm ordering covers the writes) ----
                const unsigned* lrow = (col < 8) ? &ltcpk[s0][col][0]
                                                 : &ltcpk[s1][col-8][0];
                uint4 l0q = *(const uint4*)(lrow + kb*4);
                uint4 l1q = *(const uint4*)(lrow + kb*4 + 16);
                h8v L0 = __builtin_bit_cast(h8v, l0q);
                h8v L1 = __builtin_bit_cast(h8v, l1q);
                f4v CA[2];
                #pragma unroll
                for (int nt = 0; nt < 2; ++nt) {
                    f4v c4 = {0.f, 0.f, 0.f, 0.f};
                    c4 = MFMA16(L0, wA[nt],     c4);
                    c4 = MFMA16(L1, wA[2 + nt], c4);
                    CA[nt] = c4;
                }
                #pragma unroll
                for (int r = 0; r < 4; ++r) {
                    float s = fast_tanh(CA[0][r] + ab1v[0]) * w2L[0]
                            + fast_tanh(CA[1][r] + ab1v[1]) * w2L[1];
                    s = rsum16(s);
                    float pw = fexp2(s + ab2L);
                    if (col == 0) pw_sh[kb*4 + r] = pw;
                }
                // ---- softmax accumulation (per-lane unit u = lane) ----
                #pragma unroll
                for (int t = 0; t < 16; ++t) {
                    const int sl = (t < 8) ? s0 : s1;
                    const int tr = t & 7;
                    float ltc = (float)((const _Float16*)(&ltcpk[sl][tr][0]))[lane];
                    float pwv = pw_sh[t];
                    s_run += pwv;
                    c_run += pwv * ltc;
                }
            }
        }
        ctx_sh[lane] = c_run * frcp(s_run);
    }

    __syncthreads();

    // =================== heads (by wid) ===================
    if (wid == 0) {
        float r1 = d_b1[lane];
        #pragma unroll
        for (int c = 0; c < 16; ++c) {
            float4 cq = ((const float4*)ctx_sh)[c];
            float4 wq = ((const float4*)(d_w1 + lane*64))[c];
            r1 += wq.x*cq.x + wq.y*cq.y + wq.z*cq.z + wq.w*cq.w;
        }
        r1 = fmaxf(r1, 0.0f);
        #pragma unroll
        for (int kk = 0; kk < 5; ++kk) {
            float v = d_w2[kk*64 + lane] * r1;
            v += __shfl_xor(v, 1);  v += __shfl_xor(v, 2);
            v += __shfl_xor(v, 4);  v += __shfl_xor(v, 8);
            v += __shfl_xor(v, 16); v += __shfl_xor(v, 32);
            if (lane == 0) out[b*5 + kk] = v + d_b2[kk];
        }
    } else if (wid == 1) {
        float r1 = o_b1[lane];
        #pragma unroll
        for (int c = 0; c < 16; ++c) {
            float4 cq = ((const float4*)ctx_sh)[c];
            float4 wq = ((const float4*)(o_w1 + lane*64))[c];
            r1 += wq.x*cq.x + wq.y*cq.y + wq.z*cq.z + wq.w*cq.w;
        }
        r1 = fmaxf(r1, 0.0f);
        float acc = 0.0f;
        #pragma unroll
        for (int j = 0; j < 32; ++j) {
            float rj = __shfl(r1, hb32 + j);
            acc += o_w2[u*64 + hb32 + j] * rj;
        }
        acc += __shfl_xor(acc, 32);
        float r2 = fmaxf(acc + o_b2[u], 0.0f);
        float v  = o_w3[u] * r2;
        v += __shfl_xor(v, 1);  v += __shfl_xor(v, 2);
        v += __shfl_xor(v, 4);  v += __shfl_xor(v, 8);
        v += __shfl_xor(v, 16);
        if (lane == 0) {
            float e = fexp2((v + o_b3[0]) * -L2E);
            out[5*B + b] = frcp(1.0f + e);
        }
    } else if (wid == 2) {
        float acc = 0.0f;
        #pragma unroll
        for (int c = 0; c < 8; ++c) {
            float4 cq = ((const float4*)(ctx_sh + hb32))[c];
            float4 wq = ((const float4*)(i_w1 + u*64 + hb32))[c];
            acc += wq.x*cq.x + wq.y*cq.y + wq.z*cq.z + wq.w*cq.w;
        }
        acc += __shfl_xor(acc, 32);
        float r1 = fmaxf(acc + i_b1[u], 0.0f);
        float v  = i_w2[u] * r1;
        v += __shfl_xor(v, 1);  v += __shfl_xor(v, 2);
        v += __shfl_xor(v, 4);  v += __shfl_xor(v, 8);
        v += __shfl_xor(v, 16);
        if (lane == 0) {
            float e = fexp2((v + i_b2[0]) * -L2E);
            out[6*B + b] = frcp(1.0f + e);
        }
    }
}

extern "C" void kernel_launch(void* const* d_in, const int* in_sizes, int n_in,
                              void* d_out, int out_size, void* d_ws, size_t ws_size,
                              hipStream_t stream) {
    (void)n_in; (void)out_size; (void)d_ws; (void)ws_size;
    const float* X     = (const float*)d_in[0];
    const float* fg_w1 = (const float*)d_in[1];
    const float* fg_b1 = (const float*)d_in[2];
    const float* fg_w2 = (const float*)d_in[3];
    const float* fg_b2 = (const float*)d_in[4];
    const float* fwin  = (const float*)d_in[5];
    const float* fbin  = (const float*)d_in[6];
    const float* fwrec = (const float*)d_in[7];
    const float* swin  = (const float*)d_in[8];
    const float* sbin  = (const float*)d_in[9];
    const float* swrec = (const float*)d_in[10];
    const float* fu_w  = (const float*)d_in[11];
    const float* fu_b  = (const float*)d_in[12];
    const float* at_w1 = (const float*)d_in[13];
    const float* at_b1 = (const float*)d_in[14];
    const float* at_w2 = (const float*)d_in[15];
    const float* at_b2 = (const float*)d_in[16];
    const float* d_w1  = (const float*)d_in[17];
    const float* d_b1  = (const float*)d_in[18];
    const float* d_w2  = (const float*)d_in[19];
    const float* d_b2  = (const float*)d_in[20];
    const float* o_w1  = (const float*)d_in[21];
    const float* o_b1  = (const float*)d_in[22];
    const float* o_w2  = (const float*)d_in[23];
    const float* o_b2  = (const float*)d_in[24];
    const float* o_w3  = (const float*)d_in[25];
    const float* o_b3  = (const float*)d_in[26];
    const float* i_w1  = (const float*)d_in[27];
    const float* i_b1  = (const float*)d_in[28];
    const float* i_w2  = (const float*)d_in[29];
    const float* i_b2  = (const float*)d_in[30];
    float* out = (float*)d_out;

    const int B = in_sizes[0] / (T_ * D_);
    dim3 grid(B), block(256);
    hipLaunchKernelGGL(lnn_mf, grid, block, 0, stream,
        X, fg_w1, fg_b1, fg_w2, fg_b2, fwin, fbin, fwrec, swin, sbin, swrec,
        fu_w, fu_b, at_w1, at_b1, at_w2, at_b2, d_w1, d_b1, d_w2, d_b2,
        o_w1, o_b1, o_w2, o_b2, o_w3, o_b3, i_w1, i_b1, i_w2, i_b2, out, B);
}

// Round 12
// 110.958 us; speedup vs baseline: 6.5719x; 1.1708x over previous
//
#include <hip/hip_runtime.h>

// LNNRegression R12: recurrence h-broadcast moved OFF LDS into a DPP
// butterfly all-gather (lane-permuted weights absorb the permutation).
// 4 waves, 8-step groups, NIT=70.
//   role0: x DMA + MFMA gate/y/pre + tau -> rt_sh, pre_sh  (dual-group, odd i)
//   role1: LTC recurrence BOTH cells, 1 lane/unit, in-reg butterfly (lag 2)
//          [pacer: s_setprio(1) around its step chain]
//   role2: fusion MFMA -> ltcpk ring[4]  (dual-group i-5,i-4, odd i)
//   role3: attention MFMA + static-max softmax (dual-group i-7,i-6, odd i)

#define T_  512
#define D_  31
#define GR_ 8
#define NG_ 64
#define NIT 70
#define L2E 1.4426950408889634f

typedef decltype(__builtin_amdgcn_cvt_pkrtz(0.0f, 0.0f)) h2;  // <2 x half>
typedef _Float16 h8v __attribute__((ext_vector_type(8)));
typedef float    f4v __attribute__((ext_vector_type(4)));

__device__ __forceinline__ float fexp2(float x){ return __builtin_amdgcn_exp2f(x); }
__device__ __forceinline__ float frcp (float x){ return __builtin_amdgcn_rcpf(x); }
__device__ __forceinline__ float fast_tanh(float x){
    float e = fexp2(x * 2.8853900817779268f);
    return 1.0f - 2.0f * frcp(1.0f + e);
}
__device__ __forceinline__ h2 cvt2(float a, float b){ return __builtin_amdgcn_cvt_pkrtz(a, b); }
__device__ __forceinline__ h2 bch2(unsigned v){ return __builtin_bit_cast(h2, v); }
__device__ __forceinline__ unsigned bcu(h2 v){ return __builtin_bit_cast(unsigned, v); }

template <int CTRL>
__device__ __forceinline__ float dppf(float v){
    int r = __builtin_amdgcn_update_dpp(0, __builtin_bit_cast(int, v),
                                        CTRL, 0xf, 0xf, true);
    return __builtin_bit_cast(float, r);
}
template <int CTRL>
__device__ __forceinline__ unsigned dppu(unsigned v){
    return (unsigned)__builtin_amdgcn_update_dpp(0, (int)v, CTRL, 0xf, 0xf, true);
}
__device__ __forceinline__ unsigned swz16(unsigned v){
    return (unsigned)__builtin_amdgcn_ds_swizzle((int)v, 0x401F);   // lane^16
}
__device__ __forceinline__ float rsum16(float v){
    v += dppf<0xB1>(v); v += dppf<0x4E>(v); v += dppf<0x141>(v); v += dppf<0x140>(v);
    return v;
}

#if __has_builtin(__builtin_amdgcn_fdot2)
#define FDOT2(acc, a, b) (acc) = __builtin_amdgcn_fdot2((a), (b), (acc), false)
#else
#define FDOT2(acc, a, b) (acc) += (float)(a)[0]*(float)(b)[0] + (float)(a)[1]*(float)(b)[1]
#endif

#define MFMA16(A, Bf, Cf) __builtin_amdgcn_mfma_f32_16x16x32_f16((A), (Bf), (Cf), 0, 0, 0)

#define BAR() do { asm volatile("s_waitcnt lgkmcnt(0)" ::: "memory"); \
                   __builtin_amdgcn_s_barrier();                      \
                   asm volatile("" ::: "memory"); } while (0)

__launch_bounds__(256, 4)
__global__ void lnn_mf(
    const float* __restrict__ X,
    const float* __restrict__ fg_w1, const float* __restrict__ fg_b1,
    const float* __restrict__ fg_w2, const float* __restrict__ fg_b2,
    const float* __restrict__ fwin,  const float* __restrict__ fbin,
    const float* __restrict__ fwrec,
    const float* __restrict__ swin,  const float* __restrict__ sbin,
    const float* __restrict__ swrec,
    const float* __restrict__ fu_w,  const float* __restrict__ fu_b,
    const float* __restrict__ at_w1, const float* __restrict__ at_b1,
    const float* __restrict__ at_w2, const float* __restrict__ at_b2,
    const float* __restrict__ d_w1,  const float* __restrict__ d_b1,
    const float* __restrict__ d_w2,  const float* __restrict__ d_b2,
    const float* __restrict__ o_w1,  const float* __restrict__ o_b1,
    const float* __restrict__ o_w2,  const float* __restrict__ o_b2,
    const float* __restrict__ o_w3,  const float* __restrict__ o_b3,
    const float* __restrict__ i_w1,  const float* __restrict__ i_b1,
    const float* __restrict__ i_w2,  const float* __restrict__ i_b2,
    float* __restrict__ out, int B)
{
    const int b    = blockIdx.x;
    const int tx   = threadIdx.x;
    const int wid  = tx >> 6;
    const int lane = tx & 63;
    const int u    = lane & 31;
    const int hb32 = lane & 32;
    const int role = (wid + b) & 3;

    __shared__ __align__(16) float    xr_sh [4][GR_][36];  // x ring (31+pad)
    __shared__ float    xdm   [36];                        // dummy DMA dest
    __shared__ float    pre_sh[4][GR_][65];                // pre_f|pre_s
    __shared__ float    rt_sh [4][GR_];                    // 1/tau_fast
    __shared__ __align__(16) unsigned hpk_sh[4][GR_][36];  // h packed f16x2
    __shared__ __align__(16) unsigned ltcpk [4][GR_][36];  // ltc packed f16x2
    __shared__ float    pw_sh [16];                        // softmax weights
    __shared__ float    ctx_sh[64];

    if (tx < 32) xr_sh[tx >> 3][tx & 7][31] = 0.0f;     // k=31 pad = 0

    if (role == 0) {
        // ===== role0: x DMA + MFMA gate/y/pre + y-shift + tau =====
        const int col = lane & 15, kb = lane >> 4;
        h8v wB[8];
        #pragma unroll
        for (int c = 0; c < 8; ++c) {
            float wv[8];
            #pragma unroll
            for (int j = 0; j < 8; ++j) {
                const int k = kb*8 + j;
                float v = 0.0f;
                if (k < 31) {
                    const int uu = 16*(c & 1) + col;
                    if (c < 2)      v = fg_w1[uu*62 + k] + fg_w1[uu*62 + 31 + k];
                    else if (c < 4) v = fg_w1[uu*62 + 31 + k];
                    else if (c < 6) v = fwin[uu*31 + k];
                    else            v = swin[uu*31 + k];
                }
                wv[j] = v;
            }
            uint4 qq = { bcu(cvt2(wv[0],wv[1])), bcu(cvt2(wv[2],wv[3])),
                         bcu(cvt2(wv[4],wv[5])), bcu(cvt2(wv[6],wv[7])) };
            wB[c] = __builtin_bit_cast(h8v, qq);
        }
        const float b1c[2] = { fg_b1[col], fg_b1[16 + col] };
        const float pb[4]  = { fbin[col], fbin[16+col], sbin[col], sbin[16+col] };
        const float w2n[2] = { fg_w2[col] * (-L2E), fg_w2[16+col] * (-L2E) };
        const float b2n    = fg_b2[0] * (-L2E);
        const unsigned* Xu = (const unsigned*)(X + (size_t)b * T_ * D_ + lane);
        float ypv[2] = {0.0f, 0.0f};
        asm volatile("s_waitcnt vmcnt(0)" ::: "memory");

        // prologue: DMA groups 0,1
        #pragma unroll
        for (int gg = 0; gg < 2; ++gg)
            #pragma unroll
            for (int k = 0; k < GR_; ++k)
                if (lane < 31)
                    __builtin_amdgcn_global_load_lds(
                        (const __attribute__((address_space(1))) unsigned*)(Xu + (size_t)(GR_*gg + k) * 31),
                        (__attribute__((address_space(3))) unsigned*)(&xr_sh[gg][k][0]),
                        4, 0, 0);

        for (int i = 0; i < NIT; ++i) {
            asm volatile("s_waitcnt vmcnt(8)" ::: "memory");
            BAR();
            {   // DMA group i+2 (dummy tail keeps vmcnt uniform)
                const int gq = i + 2;
                #pragma unroll
                for (int k = 0; k < GR_; ++k) {
                    int tl = GR_*gq + k; if (tl > 511) tl = 511;
                    float* dst = (gq <= NG_-1) ? &xr_sh[gq & 3][k][0] : &xdm[0];
                    if (lane < 31)
                        __builtin_amdgcn_global_load_lds(
                            (const __attribute__((address_space(1))) unsigned*)(Xu + (size_t)tl * 31),
                            (__attribute__((address_space(3))) unsigned*)dst,
                            4, 0, 0);
                }
            }
            if ((i & 1) && i <= NG_-1) {        // dual-group (i-1, i)
                const int sA_ = (i-1) & 3, sB_ = i & 3;
                const float* xrow = (col < 8) ? &xr_sh[sA_][col][kb*8]
                                              : &xr_sh[sB_][col-8][kb*8];
                float4 xa = *(const float4*)xrow;
                float4 xb = *(const float4*)(xrow + 4);
                uint4 aq = { bcu(cvt2(xa.x,xa.y)), bcu(cvt2(xa.z,xa.w)),
                             bcu(cvt2(xb.x,xb.y)), bcu(cvt2(xb.z,xb.w)) };
                h8v Af = __builtin_bit_cast(h8v, aq);
                f4v C[8];
                #pragma unroll
                for (int c = 0; c < 8; ++c) {
                    f4v z = {0.f, 0.f, 0.f, 0.f};
                    C[c] = MFMA16(Af, wB[c], z);
                }
                const int tslot = (kb < 2) ? sA_ : sB_;
                const int tb    = (kb & 1) * 4;
                float tp[4] = {0.f, 0.f, 0.f, 0.f};
                #pragma unroll
                for (int p = 0; p < 2; ++p) {
                    f4v G = C[p], Y = C[2+p];
                    if (i == 1) ypv[p] = __shfl(Y[0], col);     // dx_0 = 0
                    float ylast = __shfl(Y[3], 48 + col);       // row15 -> next
                    float yup   = __shfl(Y[3], (lane - 16) & 63);
                    float ysh0  = (kb == 0) ? ypv[p] : yup;
                    float h1v[4];
                    h1v[0] = fast_tanh(G[0] - ysh0 + b1c[p]);
                    h1v[1] = fast_tanh(G[1] - Y[0] + b1c[p]);
                    h1v[2] = fast_tanh(G[2] - Y[1] + b1c[p]);
                    h1v[3] = fast_tanh(G[3] - Y[2] + b1c[p]);
                    ypv[p] = ylast;
                    #pragma unroll
                    for (int r = 0; r < 4; ++r) tp[r] += h1v[r] * w2n[p];
                }
                #pragma unroll
                for (int r = 0; r < 4; ++r) {   // tau per row
                    float s  = rsum16(tp[r]) + b2n;
                    float cs = frcp(1.0f + fexp2(s));
                    float rt = frcp(10.0f - 9.99f * cs);
                    if (col == 0) rt_sh[tslot][tb + r] = rt;
                }
                #pragma unroll
                for (int c = 4; c < 8; ++c) {   // pre outputs
                    const int uo = (c < 6 ? 0 : 32) + 16*(c & 1) + col;
                    #pragma unroll
                    for (int r = 0; r < 4; ++r)
                        pre_sh[tslot][tb + r][uo] = C[c][r] + pb[c-4];
                }
            }
        }
        asm volatile("s_waitcnt vmcnt(0)" ::: "memory");
    } else if (role == 1) {
        // ===== role1: LTC recurrence, both cells, in-register butterfly =====
        // Butterfly reg j at lane l holds pair (h[e0], h[e1]) with
        // e0 = u^M0[j&7]^(j>=8?16:0), e1 = u^M1[j&7]^(j>=8?16:0).
        const bool slow = (lane >= 32);
        const float* W  = (slow ? swrec : fwrec) + u * 32;
        const int M0[8] = {0,2,7,5,15,13,8,10};
        const int M1[8] = {1,3,6,4,14,12,9,11};
        h2 wr[16];
        #pragma unroll
        for (int j = 0; j < 16; ++j) {
            const int x = (j & 8) ? 16 : 0;
            wr[j] = cvt2(W[u ^ M0[j & 7] ^ x], W[u ^ M1[j & 7] ^ x]);
        }
        float h_st = 0.0f;

        for (int i = 0; i < NIT; ++i) {
            BAR();
            if (i >= 2 && i <= NG_ + 1) {
                const int sR = (i - 2) & 3;
                float preA[8], rtA[8];
                #pragma unroll
                for (int k = 0; k < GR_; ++k) {
                    preA[k] = pre_sh[sR][k][lane];
                    rtA[k]  = slow ? 0.2f : rt_sh[sR][k];
                }
                __builtin_amdgcn_s_setprio(1);
                #pragma unroll
                for (int k = 0; k < GR_; ++k) {
                    float hn = dppf<0xB1>(h_st);
                    unsigned u0 = bcu(cvt2(h_st, hn));          // (l, l^1)
                    unsigned u1 = dppu<0x4E>(u0);               // ^2
                    unsigned u2 = dppu<0x141>(u0);              // ^7
                    unsigned u3 = dppu<0x141>(u1);              // ^5
                    unsigned u4 = dppu<0x140>(u0);              // ^15
                    unsigned u5 = dppu<0x140>(u1);              // ^13
                    unsigned u6 = dppu<0x140>(u2);              // ^8
                    unsigned u7 = dppu<0x140>(u3);              // ^10
                    unsigned u8  = swz16(u0), u9  = swz16(u1);
                    unsigned u10 = swz16(u2), u11 = swz16(u3);
                    unsigned u12 = swz16(u4), u13 = swz16(u5);
                    unsigned u14 = swz16(u6), u15 = swz16(u7);
                    float a0 = 0.f, a1 = 0.f, a2 = 0.f, a3 = 0.f;
                    FDOT2(a0, bch2(u0),  wr[0]);  FDOT2(a1, bch2(u1),  wr[1]);
                    FDOT2(a2, bch2(u2),  wr[2]);  FDOT2(a3, bch2(u3),  wr[3]);
                    FDOT2(a0, bch2(u4),  wr[4]);  FDOT2(a1, bch2(u5),  wr[5]);
                    FDOT2(a2, bch2(u6),  wr[6]);  FDOT2(a3, bch2(u7),  wr[7]);
                    FDOT2(a0, bch2(u8),  wr[8]);  FDOT2(a1, bch2(u9),  wr[9]);
                    FDOT2(a2, bch2(u10), wr[10]); FDOT2(a3, bch2(u11), wr[11]);
                    FDOT2(a0, bch2(u12), wr[12]); FDOT2(a1, bch2(u13), wr[13]);
                    FDOT2(a2, bch2(u14), wr[14]); FDOT2(a3, bch2(u15), wr[15]);
                    float v   = (a0 + a1) + (a2 + a3);
                    float upd = fast_tanh(v + preA[k]);
                    h_st += (upd - h_st) * rtA[k];
                    float hw = dppf<0xB1>(h_st);
                    if (!(lane & 1))
                        hpk_sh[sR][k][lane >> 1] = bcu(cvt2(h_st, hw));
                }
                __builtin_amdgcn_s_setprio(0);
            }
        }
    } else if (role == 2) {
        // ===== role2: fusion via MFMA (dual-group i-5,i-4, odd i) =====
        const int col = lane & 15, kb = lane >> 4;
        h8v wF[8];                      // [kc*4 + nc]
        #pragma unroll
        for (int kc = 0; kc < 2; ++kc)
            #pragma unroll
            for (int nc = 0; nc < 4; ++nc) {
                float wv[8];
                #pragma unroll
                for (int j = 0; j < 8; ++j)
                    wv[j] = fu_w[(16*nc + col)*64 + 32*kc + 8*kb + j];
                uint4 qq = { bcu(cvt2(wv[0],wv[1])), bcu(cvt2(wv[2],wv[3])),
                             bcu(cvt2(wv[4],wv[5])), bcu(cvt2(wv[6],wv[7])) };
                wF[kc*4 + nc] = __builtin_bit_cast(h8v, qq);
            }
        const float fb4[4] = { fu_b[col], fu_b[16+col], fu_b[32+col], fu_b[48+col] };

        for (int i = 0; i < NIT; ++i) {
            BAR();
            if ((i & 1) && i >= 5 && i <= 67) {     // dual-group (i-5, i-4)
                const int s0 = (i-5) & 3, s1 = (i-4) & 3;
                const unsigned* hrow = (col < 8) ? &hpk_sh[s0][col][0]
                                                 : &hpk_sh[s1][col-8][0];
                uint4 a0q = *(const uint4*)(hrow + kb*4);
                uint4 a1q = *(const uint4*)(hrow + kb*4 + 16);
                h8v A0 = __builtin_bit_cast(h8v, a0q);
                h8v A1 = __builtin_bit_cast(h8v, a1q);
                const int tslot = (kb < 2) ? s0 : s1;
                const int tb    = (kb & 1) * 4;
                #pragma unroll
                for (int nc = 0; nc < 4; ++nc) {
                    f4v c4 = {0.f, 0.f, 0.f, 0.f};
                    c4 = MFMA16(A0, wF[nc],     c4);
                    c4 = MFMA16(A1, wF[4 + nc], c4);
                    #pragma unroll
                    for (int r = 0; r < 4; ++r) {
                        float v  = fast_tanh(c4[r] + fb4[nc]);
                        float vn = dppf<0xB1>(v);
                        h2 pk = (col & 1) ? cvt2(vn, v) : cvt2(v, vn);
                        if (!(col & 1))
                            ltcpk[tslot][tb + r][(16*nc + col) >> 1] = bcu(pk);
                    }
                }
            }
        }
    } else {
        // ===== role3: attention MFMA + static-max softmax (i-7,i-6, odd i) ====
        const int col = lane & 15, kb = lane >> 4;
        h8v wA[4];                      // [kt*2 + nt]
        #pragma unroll
        for (int kt = 0; kt < 2; ++kt)
            #pragma unroll
            for (int nt = 0; nt < 2; ++nt) {
                float wv[8];
                #pragma unroll
                for (int j = 0; j < 8; ++j)
                    wv[j] = at_w1[(nt*16 + col)*64 + kt*32 + 8*kb + j];
                uint4 qq = { bcu(cvt2(wv[0],wv[1])), bcu(cvt2(wv[2],wv[3])),
                             bcu(cvt2(wv[4],wv[5])), bcu(cvt2(wv[6],wv[7])) };
                wA[kt*2 + nt] = __builtin_bit_cast(h8v, qq);
            }
        const float ab1v[2] = { at_b1[col], at_b1[16 + col] };
        const float w2L[2]  = { at_w2[col] * L2E, at_w2[16 + col] * L2E };
        const float ab2L    = at_b2[0] * L2E;
        float s_run = 0.0f, c_run = 0.0f;

        for (int i = 0; i < NIT; ++i) {
            BAR();
            if ((i & 1) && i >= 7) {                // dual-group (i-7, i-6)
                const int s0 = (i-7) & 3, s1 = (i-6) & 3;
                const unsigned* lrow = (col < 8) ? &ltcpk[s0][col][0]
                                                 : &ltcpk[s1][col-8][0];
                uint4 l0q = *(const uint4*)(lrow + kb*4);
                uint4 l1q = *(const uint4*)(lrow + kb*4 + 16);
                h8v L0 = __builtin_bit_cast(h8v, l0q);
                h8v L1 = __builtin_bit_cast(h8v, l1q);
                f4v CA[2];
                #pragma unroll
                for (int nt = 0; nt < 2; ++nt) {
                    f4v c4 = {0.f, 0.f, 0.f, 0.f};
                    c4 = MFMA16(L0, wA[nt],     c4);
                    c4 = MFMA16(L1, wA[2 + nt], c4);
                    CA[nt] = c4;
                }
                #pragma unroll
                for (int r = 0; r < 4; ++r) {
                    float s = fast_tanh(CA[0][r] + ab1v[0]) * w2L[0]
                            + fast_tanh(CA[1][r] + ab1v[1]) * w2L[1];
                    s = rsum16(s);
                    float pw = fexp2(s + ab2L);
                    if (col == 0) pw_sh[kb*4 + r] = pw;
                }
                #pragma unroll
                for (int t = 0; t < 16; ++t) {
                    const int sl = (t < 8) ? s0 : s1;
                    const int tr = t & 7;
                    float ltc = (float)((const _Float16*)(&ltcpk[sl][tr][0]))[lane];
                    float pwv = pw_sh[t];
                    s_run += pwv;
                    c_run += pwv * ltc;
                }
            }
        }
        ctx_sh[lane] = c_run * frcp(s_run);
    }

    __syncthreads();

    // =================== heads (by wid) ===================
    if (wid == 0) {
        float r1 = d_b1[lane];
        #pragma unroll
        for (int c = 0; c < 16; ++c) {
            float4 cq = ((const float4*)ctx_sh)[c];
            float4 wq = ((const float4*)(d_w1 + lane*64))[c];
            r1 += wq.x*cq.x + wq.y*cq.y + wq.z*cq.z + wq.w*cq.w;
        }
        r1 = fmaxf(r1, 0.0f);
        #pragma unroll
        for (int kk = 0; kk < 5; ++kk) {
            float v = d_w2[kk*64 + lane] * r1;
            v += __shfl_xor(v, 1);  v += __shfl_xor(v, 2);
            v += __shfl_xor(v, 4);  v += __shfl_xor(v, 8);
            v += __shfl_xor(v, 16); v += __shfl_xor(v, 32);
            if (lane == 0) out[b*5 + kk] = v + d_b2[kk];
        }
    } else if (wid == 1) {
        float r1 = o_b1[lane];
        #pragma unroll
        for (int c = 0; c < 16; ++c) {
            float4 cq = ((const float4*)ctx_sh)[c];
            float4 wq = ((const float4*)(o_w1 + lane*64))[c];
            r1 += wq.x*cq.x + wq.y*cq.y + wq.z*cq.z + wq.w*cq.w;
        }
        r1 = fmaxf(r1, 0.0f);
        float acc = 0.0f;
        #pragma unroll
        for (int j = 0; j < 32; ++j) {
            float rj = __shfl(r1, hb32 + j);
            acc += o_w2[u*64 + hb32 + j] * rj;
        }
        acc += __shfl_xor(acc, 32);
        float r2 = fmaxf(acc + o_b2[u], 0.0f);
        float v  = o_w3[u] * r2;
        v += __shfl_xor(v, 1);  v += __shfl_xor(v, 2);
        v += __shfl_xor(v, 4);  v += __shfl_xor(v, 8);
        v += __shfl_xor(v, 16);
        if (lane == 0) {
            float e = fexp2((v + o_b3[0]) * -L2E);
            out[5*B + b] = frcp(1.0f + e);
        }
    } else if (wid == 2) {
        float acc = 0.0f;
        #pragma unroll
        for (int c = 0; c < 8; ++c) {
            float4 cq = ((const float4*)(ctx_sh + hb32))[c];
            float4 wq = ((const float4*)(i_w1 + u*64 + hb32))[c];
            acc += wq.x*cq.x + wq.y*cq.y + wq.z*cq.z + wq.w*cq.w;
        }
        acc += __shfl_xor(acc, 32);
        float r1 = fmaxf(acc + i_b1[u], 0.0f);
        float v  = i_w2[u] * r1;
        v += __shfl_xor(v, 1);  v += __shfl_xor(v, 2);
        v += __shfl_xor(v, 4);  v += __shfl_xor(v, 8);
        v += __shfl_xor(v, 16);
        if (lane == 0) {
            float e = fexp2((v + i_b2[0]) * -L2E);
            out[6*B + b] = frcp(1.0f + e);
        }
    }
}

extern "C" void kernel_launch(void* const* d_in, const int* in_sizes, int n_in,
                              void* d_out, int out_size, void* d_ws, size_t ws_size,
                              hipStream_t stream) {
    (void)n_in; (void)out_size; (void)d_ws; (void)ws_size;
    const float* X     = (const float*)d_in[0];
    const float* fg_w1 = (const float*)d_in[1];
    const float* fg_b1 = (const float*)d_in[2];
    const float* fg_w2 = (const float*)d_in[3];
    const float* fg_b2 = (const float*)d_in[4];
    const float* fwin  = (const float*)d_in[5];
    const float* fbin  = (const float*)d_in[6];
    const float* fwrec = (const float*)d_in[7];
    const float* swin  = (const float*)d_in[8];
    const float* sbin  = (const float*)d_in[9];
    const float* swrec = (const float*)d_in[10];
    const float* fu_w  = (const float*)d_in[11];
    const float* fu_b  = (const float*)d_in[12];
    const float* at_w1 = (const float*)d_in[13];
    const float* at_b1 = (const float*)d_in[14];
    const float* at_w2 = (const float*)d_in[15];
    const float* at_b2 = (const float*)d_in[16];
    const float* d_w1  = (const float*)d_in[17];
    const float* d_b1  = (const float*)d_in[18];
    const float* d_w2  = (const float*)d_in[19];
    const float* d_b2  = (const float*)d_in[20];
    const float* o_w1  = (const float*)d_in[21];
    const float* o_b1  = (const float*)d_in[22];
    const float* o_w2  = (const float*)d_in[23];
    const float* o_b2  = (const float*)d_in[24];
    const float* o_w3  = (const float*)d_in[25];
    const float* o_b3  = (const float*)d_in[26];
    const float* i_w1  = (const float*)d_in[27];
    const float* i_b1  = (const float*)d_in[28];
    const float* i_w2  = (const float*)d_in[29];
    const float* i_b2  = (const float*)d_in[30];
    float* out = (float*)d_out;

    const int B = in_sizes[0] / (T_ * D_);
    dim3 grid(B), block(256);
    hipLaunchKernelGGL(lnn_mf, grid, block, 0, stream,
        X, fg_w1, fg_b1, fg_w2, fg_b2, fwin, fbin, fwrec, swin, sbin, swrec,
        fu_w, fu_b, at_w1, at_b1, at_w2, at_b2, d_w1, d_b1, d_w2, d_b2,
        o_w1, o_b1, o_w2, o_b2, o_w3, o_b3, i_w1, i_b1, i_w2, i_b2, out, B);
}

// Round 13
// 96.791 us; speedup vs baseline: 7.5338x; 1.1464x over previous
//
#include <hip/hip_runtime.h>

// LNNRegression R13: GR=16 (one 16-step group per iteration, NIT=36 barriers,
// half of R12's 70) + butterfly swz16 hoist (8 -> 1 LDS-pipe op per rec step).
//   role0: x DMA + MFMA gate/y/pre (M=16 rows = 16 steps) + tau -> rt/pre (lag 0)
//   role1: LTC recurrence both cells, in-reg DPP butterfly (lag 2) [setprio]
//   role2: fusion MFMA -> ltcpk ring[2] (lag 3)
//   role3: attention MFMA + static-max softmax (lag 4)

#define T_  512
#define D_  31
#define GR_ 16
#define NG_ 32
#define NIT 36
#define L2E 1.4426950408889634f

typedef decltype(__builtin_amdgcn_cvt_pkrtz(0.0f, 0.0f)) h2;  // <2 x half>
typedef _Float16 h8v __attribute__((ext_vector_type(8)));
typedef float    f4v __attribute__((ext_vector_type(4)));

__device__ __forceinline__ float fexp2(float x){ return __builtin_amdgcn_exp2f(x); }
__device__ __forceinline__ float frcp (float x){ return __builtin_amdgcn_rcpf(x); }
__device__ __forceinline__ float fast_tanh(float x){
    float e = fexp2(x * 2.8853900817779268f);
    return 1.0f - 2.0f * frcp(1.0f + e);
}
__device__ __forceinline__ h2 cvt2(float a, float b){ return __builtin_amdgcn_cvt_pkrtz(a, b); }
__device__ __forceinline__ h2 bch2(unsigned v){ return __builtin_bit_cast(h2, v); }
__device__ __forceinline__ unsigned bcu(h2 v){ return __builtin_bit_cast(unsigned, v); }

template <int CTRL>
__device__ __forceinline__ float dppf(float v){
    int r = __builtin_amdgcn_update_dpp(0, __builtin_bit_cast(int, v),
                                        CTRL, 0xf, 0xf, true);
    return __builtin_bit_cast(float, r);
}
template <int CTRL>
__device__ __forceinline__ unsigned dppu(unsigned v){
    return (unsigned)__builtin_amdgcn_update_dpp(0, (int)v, CTRL, 0xf, 0xf, true);
}
__device__ __forceinline__ unsigned swz16(unsigned v){
    return (unsigned)__builtin_amdgcn_ds_swizzle((int)v, 0x401F);   // lane^16
}
__device__ __forceinline__ float rsum16(float v){
    v += dppf<0xB1>(v); v += dppf<0x4E>(v); v += dppf<0x141>(v); v += dppf<0x140>(v);
    return v;
}

#if __has_builtin(__builtin_amdgcn_fdot2)
#define FDOT2(acc, a, b) (acc) = __builtin_amdgcn_fdot2((a), (b), (acc), false)
#else
#define FDOT2(acc, a, b) (acc) += (float)(a)[0]*(float)(b)[0] + (float)(a)[1]*(float)(b)[1]
#endif

#define MFMA16(A, Bf, Cf) __builtin_amdgcn_mfma_f32_16x16x32_f16((A), (Bf), (Cf), 0, 0, 0)

#define BAR() do { asm volatile("s_waitcnt lgkmcnt(0)" ::: "memory"); \
                   __builtin_amdgcn_s_barrier();                      \
                   asm volatile("" ::: "memory"); } while (0)

__launch_bounds__(256, 4)
__global__ void lnn_mf(
    const float* __restrict__ X,
    const float* __restrict__ fg_w1, const float* __restrict__ fg_b1,
    const float* __restrict__ fg_w2, const float* __restrict__ fg_b2,
    const float* __restrict__ fwin,  const float* __restrict__ fbin,
    const float* __restrict__ fwrec,
    const float* __restrict__ swin,  const float* __restrict__ sbin,
    const float* __restrict__ swrec,
    const float* __restrict__ fu_w,  const float* __restrict__ fu_b,
    const float* __restrict__ at_w1, const float* __restrict__ at_b1,
    const float* __restrict__ at_w2, const float* __restrict__ at_b2,
    const float* __restrict__ d_w1,  const float* __restrict__ d_b1,
    const float* __restrict__ d_w2,  const float* __restrict__ d_b2,
    const float* __restrict__ o_w1,  const float* __restrict__ o_b1,
    const float* __restrict__ o_w2,  const float* __restrict__ o_b2,
    const float* __restrict__ o_w3,  const float* __restrict__ o_b3,
    const float* __restrict__ i_w1,  const float* __restrict__ i_b1,
    const float* __restrict__ i_w2,  const float* __restrict__ i_b2,
    float* __restrict__ out, int B)
{
    const int b    = blockIdx.x;
    const int tx   = threadIdx.x;
    const int wid  = tx >> 6;
    const int lane = tx & 63;
    const int u    = lane & 31;
    const int hb32 = lane & 32;
    const int role = (wid + b) & 3;

    __shared__ __align__(16) float    xr_sh [4][GR_][36];  // x ring (31+pad)
    __shared__ float    xdm   [36];                        // dummy DMA dest
    __shared__ float    pre_sh[4][GR_][65];                // pre_f|pre_s
    __shared__ float    rt_sh [4][GR_];                    // 1/tau_fast
    __shared__ __align__(16) unsigned hpk_sh[2][GR_][36];  // h packed f16x2
    __shared__ __align__(16) unsigned ltcpk [2][GR_][36];  // ltc packed f16x2
    __shared__ float    pw_sh [GR_];                       // softmax weights
    __shared__ float    ctx_sh[64];

    if (tx < 64) xr_sh[tx >> 4][tx & 15][31] = 0.0f;    // k=31 pad = 0

    if (role == 0) {
        // ===== role0: x DMA + MFMA gate/y/pre + y-shift + tau (lag 0) =====
        const int col = lane & 15, kb = lane >> 4;
        h8v wB[8];
        #pragma unroll
        for (int c = 0; c < 8; ++c) {
            float wv[8];
            #pragma unroll
            for (int j = 0; j < 8; ++j) {
                const int k = kb*8 + j;
                float v = 0.0f;
                if (k < 31) {
                    const int uu = 16*(c & 1) + col;
                    if (c < 2)      v = fg_w1[uu*62 + k] + fg_w1[uu*62 + 31 + k];
                    else if (c < 4) v = fg_w1[uu*62 + 31 + k];
                    else if (c < 6) v = fwin[uu*31 + k];
                    else            v = swin[uu*31 + k];
                }
                wv[j] = v;
            }
            uint4 qq = { bcu(cvt2(wv[0],wv[1])), bcu(cvt2(wv[2],wv[3])),
                         bcu(cvt2(wv[4],wv[5])), bcu(cvt2(wv[6],wv[7])) };
            wB[c] = __builtin_bit_cast(h8v, qq);
        }
        const float b1c[2] = { fg_b1[col], fg_b1[16 + col] };
        const float pb[4]  = { fbin[col], fbin[16+col], sbin[col], sbin[16+col] };
        const float w2n[2] = { fg_w2[col] * (-L2E), fg_w2[16+col] * (-L2E) };
        const float b2n    = fg_b2[0] * (-L2E);
        const unsigned* Xu = (const unsigned*)(X + (size_t)b * T_ * D_ + lane);
        float ypv[2] = {0.0f, 0.0f};
        asm volatile("s_waitcnt vmcnt(0)" ::: "memory");

        // prologue: DMA groups 0,1 (32 loads)
        #pragma unroll
        for (int gg = 0; gg < 2; ++gg)
            #pragma unroll
            for (int k = 0; k < GR_; ++k)
                if (lane < 31)
                    __builtin_amdgcn_global_load_lds(
                        (const __attribute__((address_space(1))) unsigned*)(Xu + (size_t)(GR_*gg + k) * 31),
                        (__attribute__((address_space(3))) unsigned*)(&xr_sh[gg][k][0]),
                        4, 0, 0);

        for (int i = 0; i < NIT; ++i) {
            asm volatile("s_waitcnt vmcnt(16)" ::: "memory");  // group i landed
            BAR();
            {   // DMA group i+2 (dummy tail keeps vmcnt uniform)
                const int gq = i + 2;
                #pragma unroll
                for (int k = 0; k < GR_; ++k) {
                    int tl = GR_*gq + k; if (tl > 511) tl = 511;
                    float* dst = (gq <= NG_-1) ? &xr_sh[gq & 3][k][0] : &xdm[0];
                    if (lane < 31)
                        __builtin_amdgcn_global_load_lds(
                            (const __attribute__((address_space(1))) unsigned*)(Xu + (size_t)tl * 31),
                            (__attribute__((address_space(3))) unsigned*)dst,
                            4, 0, 0);
                }
            }
            if (i <= NG_-1) {
                const int sG = i & 3;
                const float* xrow = &xr_sh[sG][col][kb*8];
                float4 xa = *(const float4*)xrow;
                float4 xb = *(const float4*)(xrow + 4);
                uint4 aq = { bcu(cvt2(xa.x,xa.y)), bcu(cvt2(xa.z,xa.w)),
                             bcu(cvt2(xb.x,xb.y)), bcu(cvt2(xb.z,xb.w)) };
                h8v Af = __builtin_bit_cast(h8v, aq);
                f4v C[8];
                #pragma unroll
                for (int c = 0; c < 8; ++c) {
                    f4v z = {0.f, 0.f, 0.f, 0.f};
                    C[c] = MFMA16(Af, wB[c], z);
                }
                const int tb = kb * 4;          // row = timestep kb*4+r
                float tp[4] = {0.f, 0.f, 0.f, 0.f};
                #pragma unroll
                for (int p = 0; p < 2; ++p) {
                    f4v G = C[p], Y = C[2+p];
                    if (i == 0) ypv[p] = __shfl(Y[0], col);     // dx_0 = 0
                    float ylast = __shfl(Y[3], 48 + col);       // row15 -> next
                    float yup   = __shfl(Y[3], (lane - 16) & 63);
                    float ysh0  = (kb == 0) ? ypv[p] : yup;
                    float h1v[4];
                    h1v[0] = fast_tanh(G[0] - ysh0 + b1c[p]);
                    h1v[1] = fast_tanh(G[1] - Y[0] + b1c[p]);
                    h1v[2] = fast_tanh(G[2] - Y[1] + b1c[p]);
                    h1v[3] = fast_tanh(G[3] - Y[2] + b1c[p]);
                    ypv[p] = ylast;
                    #pragma unroll
                    for (int r = 0; r < 4; ++r) tp[r] += h1v[r] * w2n[p];
                }
                #pragma unroll
                for (int r = 0; r < 4; ++r) {   // tau per row
                    float s  = rsum16(tp[r]) + b2n;
                    float cs = frcp(1.0f + fexp2(s));
                    float rt = frcp(10.0f - 9.99f * cs);
                    if (col == 0) rt_sh[sG][tb + r] = rt;
                }
                #pragma unroll
                for (int c = 4; c < 8; ++c) {   // pre outputs
                    const int uo = (c < 6 ? 0 : 32) + 16*(c & 1) + col;
                    #pragma unroll
                    for (int r = 0; r < 4; ++r)
                        pre_sh[sG][tb + r][uo] = C[c][r] + pb[c-4];
                }
            }
        }
        asm volatile("s_waitcnt vmcnt(0)" ::: "memory");
    } else if (role == 1) {
        // ===== role1: LTC recurrence, both cells, in-register butterfly =====
        const bool slow = (lane >= 32);
        const float* W  = (slow ? swrec : fwrec) + u * 32;
        const int M0[8] = {0,2,7,5,15,13,8,10};
        const int M1[8] = {1,3,6,4,14,12,9,11};
        h2 wr[16];
        #pragma unroll
        for (int j = 0; j < 16; ++j) {
            const int x = (j & 8) ? 16 : 0;
            wr[j] = cvt2(W[u ^ M0[j & 7] ^ x], W[u ^ M1[j & 7] ^ x]);
        }
        float h_st = 0.0f;

        for (int i = 0; i < NIT; ++i) {
            BAR();
            if (i >= 2 && i <= NG_ + 1) {
                const int gR = i - 2;
                const int sR = gR & 3;
                const int sH = gR & 1;
                float preA[GR_], rtA[GR_];
                #pragma unroll
                for (int k = 0; k < GR_; ++k) {
                    preA[k] = pre_sh[sR][k][lane];
                    rtA[k]  = slow ? 0.2f : rt_sh[sR][k];
                }
                __builtin_amdgcn_s_setprio(1);
                #pragma unroll
                for (int k = 0; k < GR_; ++k) {
                    float hn = dppf<0xB1>(h_st);
                    unsigned u0 = bcu(cvt2(h_st, hn));          // (l, l^1)
                    unsigned w0 = swz16(u0);                    // ^16 (1 LDS op)
                    unsigned u1 = dppu<0x4E>(u0);               // ^2
                    unsigned u2 = dppu<0x141>(u0);              // ^7
                    unsigned u3 = dppu<0x141>(u1);              // ^5
                    unsigned u4 = dppu<0x140>(u0);              // ^15
                    unsigned u5 = dppu<0x140>(u1);              // ^13
                    unsigned u6 = dppu<0x140>(u2);              // ^8
                    unsigned u7 = dppu<0x140>(u3);              // ^10
                    unsigned w1 = dppu<0x4E>(w0);
                    unsigned w2 = dppu<0x141>(w0);
                    unsigned w3 = dppu<0x141>(w1);
                    unsigned w4 = dppu<0x140>(w0);
                    unsigned w5 = dppu<0x140>(w1);
                    unsigned w6 = dppu<0x140>(w2);
                    unsigned w7 = dppu<0x140>(w3);
                    float a0 = 0.f, a1 = 0.f, a2 = 0.f, a3 = 0.f;
                    FDOT2(a0, bch2(u0), wr[0]);  FDOT2(a1, bch2(u1), wr[1]);
                    FDOT2(a2, bch2(u2), wr[2]);  FDOT2(a3, bch2(u3), wr[3]);
                    FDOT2(a0, bch2(u4), wr[4]);  FDOT2(a1, bch2(u5), wr[5]);
                    FDOT2(a2, bch2(u6), wr[6]);  FDOT2(a3, bch2(u7), wr[7]);
                    FDOT2(a0, bch2(w0), wr[8]);  FDOT2(a1, bch2(w1), wr[9]);
                    FDOT2(a2, bch2(w2), wr[10]); FDOT2(a3, bch2(w3), wr[11]);
                    FDOT2(a0, bch2(w4), wr[12]); FDOT2(a1, bch2(w5), wr[13]);
                    FDOT2(a2, bch2(w6), wr[14]); FDOT2(a3, bch2(w7), wr[15]);
                    float v   = (a0 + a1) + (a2 + a3);
                    float upd = fast_tanh(v + preA[k]);
                    h_st += (upd - h_st) * rtA[k];
                    float hw = dppf<0xB1>(h_st);
                    if (!(lane & 1))
                        hpk_sh[sH][k][lane >> 1] = bcu(cvt2(h_st, hw));
                }
                __builtin_amdgcn_s_setprio(0);
            }
        }
    } else if (role == 2) {
        // ===== role2: fusion via MFMA (lag 3) =====
        const int col = lane & 15, kb = lane >> 4;
        h8v wF[8];                      // [kc*4 + nc]
        #pragma unroll
        for (int kc = 0; kc < 2; ++kc)
            #pragma unroll
            for (int nc = 0; nc < 4; ++nc) {
                float wv[8];
                #pragma unroll
                for (int j = 0; j < 8; ++j)
                    wv[j] = fu_w[(16*nc + col)*64 + 32*kc + 8*kb + j];
                uint4 qq = { bcu(cvt2(wv[0],wv[1])), bcu(cvt2(wv[2],wv[3])),
                             bcu(cvt2(wv[4],wv[5])), bcu(cvt2(wv[6],wv[7])) };
                wF[kc*4 + nc] = __builtin_bit_cast(h8v, qq);
            }
        const float fb4[4] = { fu_b[col], fu_b[16+col], fu_b[32+col], fu_b[48+col] };

        for (int i = 0; i < NIT; ++i) {
            BAR();
            if (i >= 3 && i <= NG_ + 2) {
                const int gF = i - 3;
                const int sH = gF & 1;
                const unsigned* hrow = &hpk_sh[sH][col][0];
                uint4 a0q = *(const uint4*)(hrow + kb*4);
                uint4 a1q = *(const uint4*)(hrow + kb*4 + 16);
                h8v A0 = __builtin_bit_cast(h8v, a0q);
                h8v A1 = __builtin_bit_cast(h8v, a1q);
                const int tb = kb * 4;
                #pragma unroll
                for (int nc = 0; nc < 4; ++nc) {
                    f4v c4 = {0.f, 0.f, 0.f, 0.f};
                    c4 = MFMA16(A0, wF[nc],     c4);
                    c4 = MFMA16(A1, wF[4 + nc], c4);
                    #pragma unroll
                    for (int r = 0; r < 4; ++r) {
                        float v  = fast_tanh(c4[r] + fb4[nc]);
                        float vn = dppf<0xB1>(v);
                        h2 pk = (col & 1) ? cvt2(vn, v) : cvt2(v, vn);
                        if (!(col & 1))
                            ltcpk[gF & 1][tb + r][(16*nc + col) >> 1] = bcu(pk);
                    }
                }
            }
        }
    } else {
        // ===== role3: attention MFMA + static-max softmax (lag 4) =====
        const int col = lane & 15, kb = lane >> 4;
        h8v wA[4];                      // [kt*2 + nt]
        #pragma unroll
        for (int kt = 0; kt < 2; ++kt)
            #pragma unroll
            for (int nt = 0; nt < 2; ++nt) {
                float wv[8];
                #pragma unroll
                for (int j = 0; j < 8; ++j)
                    wv[j] = at_w1[(nt*16 + col)*64 + kt*32 + 8*kb + j];
                uint4 qq = { bcu(cvt2(wv[0],wv[1])), bcu(cvt2(wv[2],wv[3])),
                             bcu(cvt2(wv[4],wv[5])), bcu(cvt2(wv[6],wv[7])) };
                wA[kt*2 + nt] = __builtin_bit_cast(h8v, qq);
            }
        const float ab1v[2] = { at_b1[col], at_b1[16 + col] };
        const float w2L[2]  = { at_w2[col] * L2E, at_w2[16 + col] * L2E };
        const float ab2L    = at_b2[0] * L2E;
        float s_run = 0.0f, c_run = 0.0f;

        for (int i = 0; i < NIT; ++i) {
            BAR();
            if (i >= 4) {                       // group i-4 (<= NG_-1 automatic)
                const int gA = i - 4;
                const int sl = gA & 1;
                const unsigned* lrow = &ltcpk[sl][col][0];
                uint4 l0q = *(const uint4*)(lrow + kb*4);
                uint4 l1q = *(const uint4*)(lrow + kb*4 + 16);
                h8v L0 = __builtin_bit_cast(h8v, l0q);
                h8v L1 = __builtin_bit_cast(h8v, l1q);
                f4v CA[2];
                #pragma unroll
                for (int nt = 0; nt < 2; ++nt) {
                    f4v c4 = {0.f, 0.f, 0.f, 0.f};
                    c4 = MFMA16(L0, wA[nt],     c4);
                    c4 = MFMA16(L1, wA[2 + nt], c4);
                    CA[nt] = c4;
                }
                #pragma unroll
                for (int r = 0; r < 4; ++r) {
                    float s = fast_tanh(CA[0][r] + ab1v[0]) * w2L[0]
                            + fast_tanh(CA[1][r] + ab1v[1]) * w2L[1];
                    s = rsum16(s);
                    float pw = fexp2(s + ab2L);
                    if (col == 0) pw_sh[kb*4 + r] = pw;
                }
                #pragma unroll
                for (int t = 0; t < GR_; ++t) {
                    float ltc = (float)((const _Float16*)(&ltcpk[sl][t][0]))[lane];
                    float pwv = pw_sh[t];
                    s_run += pwv;
                    c_run += pwv * ltc;
                }
            }
        }
        ctx_sh[lane] = c_run * frcp(s_run);
    }

    __syncthreads();

    // =================== heads (by wid) ===================
    if (wid == 0) {
        float r1 = d_b1[lane];
        #pragma unroll
        for (int c = 0; c < 16; ++c) {
            float4 cq = ((const float4*)ctx_sh)[c];
            float4 wq = ((const float4*)(d_w1 + lane*64))[c];
            r1 += wq.x*cq.x + wq.y*cq.y + wq.z*cq.z + wq.w*cq.w;
        }
        r1 = fmaxf(r1, 0.0f);
        #pragma unroll
        for (int kk = 0; kk < 5; ++kk) {
            float v = d_w2[kk*64 + lane] * r1;
            v += __shfl_xor(v, 1);  v += __shfl_xor(v, 2);
            v += __shfl_xor(v, 4);  v += __shfl_xor(v, 8);
            v += __shfl_xor(v, 16); v += __shfl_xor(v, 32);
            if (lane == 0) out[b*5 + kk] = v + d_b2[kk];
        }
    } else if (wid == 1) {
        float r1 = o_b1[lane];
        #pragma unroll
        for (int c = 0; c < 16; ++c) {
            float4 cq = ((const float4*)ctx_sh)[c];
            float4 wq = ((const float4*)(o_w1 + lane*64))[c];
            r1 += wq.x*cq.x + wq.y*cq.y + wq.z*cq.z + wq.w*cq.w;
        }
        r1 = fmaxf(r1, 0.0f);
        float acc = 0.0f;
        #pragma unroll
        for (int j = 0; j < 32; ++j) {
            float rj = __shfl(r1, hb32 + j);
            acc += o_w2[u*64 + hb32 + j] * rj;
        }
        acc += __shfl_xor(acc, 32);
        float r2 = fmaxf(acc + o_b2[u], 0.0f);
        float v  = o_w3[u] * r2;
        v += __shfl_xor(v, 1);  v += __shfl_xor(v, 2);
        v += __shfl_xor(v, 4);  v += __shfl_xor(v, 8);
        v += __shfl_xor(v, 16);
        if (lane == 0) {
            float e = fexp2((v + o_b3[0]) * -L2E);
            out[5*B + b] = frcp(1.0f + e);
        }
    } else if (wid == 2) {
        float acc = 0.0f;
        #pragma unroll
        for (int c = 0; c < 8; ++c) {
            float4 cq = ((const float4*)(ctx_sh + hb32))[c];
            float4 wq = ((const float4*)(i_w1 + u*64 + hb32))[c];
            acc += wq.x*cq.x + wq.y*cq.y + wq.z*cq.z + wq.w*cq.w;
        }
        acc += __shfl_xor(acc, 32);
        float r1 = fmaxf(acc + i_b1[u], 0.0f);
        float v  = i_w2[u] * r1;
        v += __shfl_xor(v, 1);  v += __shfl_xor(v, 2);
        v += __shfl_xor(v, 4);  v += __shfl_xor(v, 8);
        v += __shfl_xor(v, 16);
        if (lane == 0) {
            float e = fexp2((v + i_b2[0]) * -L2E);
            out[6*B + b] = frcp(1.0f + e);
        }
    }
}

extern "C" void kernel_launch(void* const* d_in, const int* in_sizes, int n_in,
                              void* d_out, int out_size, void* d_ws, size_t ws_size,
                              hipStream_t stream) {
    (void)n_in; (void)out_size; (void)d_ws; (void)ws_size;
    const float* X     = (const float*)d_in[0];
    const float* fg_w1 = (const float*)d_in[1];
    const float* fg_b1 = (const float*)d_in[2];
    const float* fg_w2 = (const float*)d_in[3];
    const float* fg_b2 = (const float*)d_in[4];
    const float* fwin  = (const float*)d_in[5];
    const float* fbin  = (const float*)d_in[6];
    const float* fwrec = (const float*)d_in[7];
    const float* swin  = (const float*)d_in[8];
    const float* sbin  = (const float*)d_in[9];
    const float* swrec = (const float*)d_in[10];
    const float* fu_w  = (const float*)d_in[11];
    const float* fu_b  = (const float*)d_in[12];
    const float* at_w1 = (const float*)d_in[13];
    const float* at_b1 = (const float*)d_in[14];
    const float* at_w2 = (const float*)d_in[15];
    const float* at_b2 = (const float*)d_in[16];
    const float* d_w1  = (const float*)d_in[17];
    const float* d_b1  = (const float*)d_in[18];
    const float* d_w2  = (const float*)d_in[19];
    const float* d_b2  = (const float*)d_in[20];
    const float* o_w1  = (const float*)d_in[21];
    const float* o_b1  = (const float*)d_in[22];
    const float* o_w2  = (const float*)d_in[23];
    const float* o_b2  = (const float*)d_in[24];
    const float* o_w3  = (const float*)d_in[25];
    const float* o_b3  = (const float*)d_in[26];
    const float* i_w1  = (const float*)d_in[27];
    const float* i_b1  = (const float*)d_in[28];
    const float* i_w2  = (const float*)d_in[29];
    const float* i_b2  = (const float*)d_in[30];
    float* out = (float*)d_out;

    const int B = in_sizes[0] / (T_ * D_);
    dim3 grid(B), block(256);
    hipLaunchKernelGGL(lnn_mf, grid, block, 0, stream,
        X, fg_w1, fg_b1, fg_w2, fg_b2, fwin, fbin, fwrec, swin, sbin, swrec,
        fu_w, fu_b, at_w1, at_b1, at_w2, at_b2, d_w1, d_b1, d_w2, d_b2,
        o_w1, o_b1, o_w2, o_b2, o_w3, o_b3, i_w1, i_b1, i_w2, i_b2, out, B);
}